// Round 1
// baseline (4444.006 us; speedup 1.0000x reference)
//
#include <hip/hip_runtime.h>

#define EPS_F 1e-10f

// ---------------------------------------------------------------------------
// Kernel A: init outputs.
// out0 row r = [ mu[r][0:256], zeros(256) ], out1 row r = [ var[r][0:256], zeros(256) ]
// One 256-thread block per row; threads 0..127 cover out0's 128 float4s,
// threads 128..255 cover out1's.
// ---------------------------------------------------------------------------
__global__ __launch_bounds__(256) void k_init_out(
    const float* __restrict__ mu, const float* __restrict__ var,
    float* __restrict__ out0, float* __restrict__ out1) {
  int r = blockIdx.x;
  int t = threadIdx.x;
  const float4 z = make_float4(0.f, 0.f, 0.f, 0.f);
  if (t < 128) {
    float4* dst = (float4*)(out0 + (size_t)r * 512);
    dst[t] = (t < 64) ? ((const float4*)(mu + (size_t)r * 256))[t] : z;
  } else {
    int u = t - 128;
    float4* dst = (float4*)(out1 + (size_t)r * 512);
    dst[u] = (u < 64) ? ((const float4*)(var + (size_t)r * 256))[u] : z;
  }
}

// ---------------------------------------------------------------------------
// Kernel B: precompute per-input-row intermediates into workspace.
// dmu = mu - mu_history[ifield];  ds2 = (sqrt(var)-sqrt(varh))^2; ms = ds*sqrt(varh)
// One wave per row, lane l handles float4 l (256 floats per row).
// ---------------------------------------------------------------------------
__global__ __launch_bounds__(256) void k_pre(
    const float* __restrict__ mu, const float* __restrict__ var,
    const float* __restrict__ muh, const float* __restrict__ varh,
    const int* __restrict__ ifield,
    float* __restrict__ dmu, float* __restrict__ ds2, float* __restrict__ ms,
    int n_in) {
  int wave = (int)((blockIdx.x * blockDim.x + threadIdx.x) >> 6);
  int lane = threadIdx.x & 63;
  int nw = (int)((gridDim.x * blockDim.x) >> 6);
  for (int row = wave; row < n_in; row += nw) {
    int f = ifield[row];
    float4 m  = ((const float4*)(mu   + (size_t)row * 256))[lane];
    float4 v  = ((const float4*)(var  + (size_t)row * 256))[lane];
    float4 mh = ((const float4*)(muh  + (size_t)f   * 256))[lane];
    float4 vh = ((const float4*)(varh + (size_t)f   * 256))[lane];
    float4 d, q, p;
    {
      float s, sb, ds;
      s = sqrtf(v.x); sb = sqrtf(vh.x); ds = s - sb; d.x = m.x - mh.x; q.x = ds * ds; p.x = ds * sb;
      s = sqrtf(v.y); sb = sqrtf(vh.y); ds = s - sb; d.y = m.y - mh.y; q.y = ds * ds; p.y = ds * sb;
      s = sqrtf(v.z); sb = sqrtf(vh.z); ds = s - sb; d.z = m.z - mh.z; q.z = ds * ds; p.z = ds * sb;
      s = sqrtf(v.w); sb = sqrtf(vh.w); ds = s - sb; d.w = m.w - mh.w; q.w = ds * ds; p.w = ds * sb;
    }
    ((float4*)(dmu + (size_t)row * 256))[lane] = d;
    ((float4*)(ds2 + (size_t)row * 256))[lane] = q;
    ((float4*)(ms  + (size_t)row * 256))[lane] = p;
  }
}

// ---------------------------------------------------------------------------
// Kernel C: adj edges. Per edge: out_mu[row] += w*dmu[col]; out_var[row] += w^2*ds2[col].
// One wave per edge iteration; lane covers float4 of the 256-wide row.
// PRE=true reads precomputed ws; PRE=false recomputes via gathers.
// ---------------------------------------------------------------------------
template <bool PRE>
__global__ __launch_bounds__(256) void k_edge_adj(
    const float* __restrict__ vals, const int* __restrict__ rows,
    const int* __restrict__ cols,
    const float* __restrict__ dmu, const float* __restrict__ ds2,
    const float* __restrict__ mu, const float* __restrict__ var,
    const float* __restrict__ muh, const float* __restrict__ varh,
    const int* __restrict__ ifield,
    float* __restrict__ out0, float* __restrict__ out1, int nnz) {
  int wave = (int)((blockIdx.x * blockDim.x + threadIdx.x) >> 6);
  int lane = threadIdx.x & 63;
  int nw = (int)((gridDim.x * blockDim.x) >> 6);
  for (int e = wave; e < nnz; e += nw) {
    float w = vals[e];
    int r = rows[e];
    int c = cols[e];
    float4 xm, xv;
    if (PRE) {
      xm = ((const float4*)(dmu + (size_t)c * 256))[lane];
      xv = ((const float4*)(ds2 + (size_t)c * 256))[lane];
    } else {
      int f = ifield[c];
      float4 m  = ((const float4*)(mu   + (size_t)c * 256))[lane];
      float4 v  = ((const float4*)(var  + (size_t)c * 256))[lane];
      float4 mh = ((const float4*)(muh  + (size_t)f * 256))[lane];
      float4 vh = ((const float4*)(varh + (size_t)f * 256))[lane];
      float ds;
      xm.x = m.x - mh.x; ds = sqrtf(v.x) - sqrtf(vh.x); xv.x = ds * ds;
      xm.y = m.y - mh.y; ds = sqrtf(v.y) - sqrtf(vh.y); xv.y = ds * ds;
      xm.z = m.z - mh.z; ds = sqrtf(v.z) - sqrtf(vh.z); xv.z = ds * ds;
      xm.w = m.w - mh.w; ds = sqrtf(v.w) - sqrtf(vh.w); xv.w = ds * ds;
    }
    float w2 = w * w;
    float* om = out0 + (size_t)r * 512 + 256 + lane * 4;
    float* ov = out1 + (size_t)r * 512 + 256 + lane * 4;
    atomicAdd(om + 0, w * xm.x);
    atomicAdd(om + 1, w * xm.y);
    atomicAdd(om + 2, w * xm.z);
    atomicAdd(om + 3, w * xm.w);
    atomicAdd(ov + 0, w2 * xv.x);
    atomicAdd(ov + 1, w2 * xv.y);
    atomicAdd(ov + 2, w2 * xv.z);
    atomicAdd(ov + 3, w2 * xv.w);
  }
}

// ---------------------------------------------------------------------------
// Kernel D: fadj edges. out_mu[row] += w*mu_history[ffield[col]];
//                      out_var[row] += w^2*var_history[ffield[col]].
// (No precompute needed — pure gather.)
// ---------------------------------------------------------------------------
__global__ __launch_bounds__(256) void k_edge_fadj(
    const float* __restrict__ vals, const int* __restrict__ rows,
    const int* __restrict__ cols,
    const float* __restrict__ muh, const float* __restrict__ varh,
    const int* __restrict__ ffield,
    float* __restrict__ out0, float* __restrict__ out1, int nnz) {
  int wave = (int)((blockIdx.x * blockDim.x + threadIdx.x) >> 6);
  int lane = threadIdx.x & 63;
  int nw = (int)((gridDim.x * blockDim.x) >> 6);
  for (int e = wave; e < nnz; e += nw) {
    float w = vals[e];
    int r = rows[e];
    int c = cols[e];
    int f = ffield[c];
    float4 mb = ((const float4*)(muh  + (size_t)f * 256))[lane];
    float4 vb = ((const float4*)(varh + (size_t)f * 256))[lane];
    float w2 = w * w;
    float* om = out0 + (size_t)r * 512 + 256 + lane * 4;
    float* ov = out1 + (size_t)r * 512 + 256 + lane * 4;
    atomicAdd(om + 0, w * mb.x);
    atomicAdd(om + 1, w * mb.y);
    atomicAdd(om + 2, w * mb.z);
    atomicAdd(om + 3, w * mb.w);
    atomicAdd(ov + 0, w2 * vb.x);
    atomicAdd(ov + 1, w2 * vb.y);
    atomicAdd(ov + 2, w2 * vb.z);
    atomicAdd(ov + 3, w2 * vb.w);
  }
}

// ---------------------------------------------------------------------------
// Kernel E: madj edges. out_var[row] += 2*w*msigma[col].
// ---------------------------------------------------------------------------
template <bool PRE>
__global__ __launch_bounds__(256) void k_edge_madj(
    const float* __restrict__ vals, const int* __restrict__ rows,
    const int* __restrict__ cols,
    const float* __restrict__ ms,
    const float* __restrict__ var, const float* __restrict__ varh,
    const int* __restrict__ ifield,
    float* __restrict__ out1, int nnz) {
  int wave = (int)((blockIdx.x * blockDim.x + threadIdx.x) >> 6);
  int lane = threadIdx.x & 63;
  int nw = (int)((gridDim.x * blockDim.x) >> 6);
  for (int e = wave; e < nnz; e += nw) {
    float w = 2.0f * vals[e];
    int r = rows[e];
    int c = cols[e];
    float4 x;
    if (PRE) {
      x = ((const float4*)(ms + (size_t)c * 256))[lane];
    } else {
      int f = ifield[c];
      float4 v  = ((const float4*)(var  + (size_t)c * 256))[lane];
      float4 vh = ((const float4*)(varh + (size_t)f * 256))[lane];
      float sb;
      sb = sqrtf(vh.x); x.x = (sqrtf(v.x) - sb) * sb;
      sb = sqrtf(vh.y); x.y = (sqrtf(v.y) - sb) * sb;
      sb = sqrtf(vh.z); x.z = (sqrtf(v.z) - sb) * sb;
      sb = sqrtf(vh.w); x.w = (sqrtf(v.w) - sb) * sb;
    }
    float* ov = out1 + (size_t)r * 512 + 256 + lane * 4;
    atomicAdd(ov + 0, w * x.x);
    atomicAdd(ov + 1, w * x.y);
    atomicAdd(ov + 2, w * x.z);
    atomicAdd(ov + 3, w * x.w);
  }
}

// ---------------------------------------------------------------------------
// Kernel F: relu + EPS on the var-neighbour half of out1.
// ---------------------------------------------------------------------------
__global__ __launch_bounds__(256) void k_final(float* __restrict__ out1, int n_out) {
  int total = n_out * 64;  // float4 count of the neighbour halves
  for (int i = blockIdx.x * blockDim.x + threadIdx.x; i < total;
       i += gridDim.x * blockDim.x) {
    int r = i >> 6;
    int q = i & 63;
    float4* p = (float4*)(out1 + (size_t)r * 512 + 256) + q;
    float4 v = *p;
    v.x = fmaxf(v.x, 0.f) + EPS_F;
    v.y = fmaxf(v.y, 0.f) + EPS_F;
    v.z = fmaxf(v.z, 0.f) + EPS_F;
    v.w = fmaxf(v.w, 0.f) + EPS_F;
    *p = v;
  }
}

extern "C" void kernel_launch(void* const* d_in, const int* in_sizes, int n_in_args,
                              void* d_out, int out_size, void* d_ws, size_t ws_size,
                              hipStream_t stream) {
  const float* mu        = (const float*)d_in[0];
  const float* var       = (const float*)d_in[1];
  const float* muh       = (const float*)d_in[2];
  const float* varh      = (const float*)d_in[3];
  const float* adj_vals  = (const float*)d_in[4];
  const float* fadj_vals = (const float*)d_in[5];
  const float* madj_vals = (const float*)d_in[6];
  const int* adj_rows    = (const int*)d_in[7];
  const int* adj_cols    = (const int*)d_in[8];
  const int* fadj_rows   = (const int*)d_in[9];
  const int* fadj_cols   = (const int*)d_in[10];
  const int* madj_rows   = (const int*)d_in[11];
  const int* madj_cols   = (const int*)d_in[12];
  const int* ifield      = (const int*)d_in[13];
  const int* ffield      = (const int*)d_in[14];

  const int n_out = out_size / 1024;   // two outputs of 512 cols each
  const int n_in  = in_sizes[0] / 256; // d = 256
  const int nnz   = in_sizes[4];

  float* out0 = (float*)d_out;
  float* out1 = out0 + (size_t)n_out * 512;

  const size_t need = (size_t)n_in * 256 * 3 * sizeof(float);
  const bool pre = (ws_size >= need);
  float* dmu = (float*)d_ws;
  float* ds2 = dmu + (size_t)n_in * 256;
  float* ms  = ds2 + (size_t)n_in * 256;

  // A: self-copy + zero neighbour halves (must run every call).
  k_init_out<<<n_out, 256, 0, stream>>>(mu, var, out0, out1);

  if (pre) {
    // B: precompute intermediates.
    k_pre<<<4096, 256, 0, stream>>>(mu, var, muh, varh, ifield, dmu, ds2, ms, n_in);
    // C/E: edge passes reading precomputed ws.
    k_edge_adj<true><<<4096, 256, 0, stream>>>(adj_vals, adj_rows, adj_cols, dmu, ds2,
                                               mu, var, muh, varh, ifield, out0, out1, nnz);
    k_edge_madj<true><<<4096, 256, 0, stream>>>(madj_vals, madj_rows, madj_cols, ms,
                                                var, varh, ifield, out1, nnz);
  } else {
    k_edge_adj<false><<<4096, 256, 0, stream>>>(adj_vals, adj_rows, adj_cols, nullptr, nullptr,
                                                mu, var, muh, varh, ifield, out0, out1, nnz);
    k_edge_madj<false><<<4096, 256, 0, stream>>>(madj_vals, madj_rows, madj_cols, nullptr,
                                                 var, varh, ifield, out1, nnz);
  }
  // D: fadj gathers history directly.
  k_edge_fadj<<<4096, 256, 0, stream>>>(fadj_vals, fadj_rows, fadj_cols, muh, varh, ffield,
                                        out0, out1, nnz);
  // F: relu + eps epilogue.
  k_final<<<4096, 256, 0, stream>>>(out1, n_out);
}

// Round 2
// 502.418 us; speedup vs baseline: 8.8452x; 8.8452x over previous
//
#include <hip/hip_runtime.h>

#define EPS_F 1e-10f

// ===========================================================================
// CSR-build helpers (COO rows -> per-row edge lists, built on device per call)
// ===========================================================================
__global__ void k_zero_i32(int* __restrict__ p, int n) {
  for (int i = blockIdx.x * blockDim.x + threadIdx.x; i < n;
       i += gridDim.x * blockDim.x)
    p[i] = 0;
}

__global__ void k_count(const int* __restrict__ rows, int* __restrict__ cnt, int nnz) {
  for (int e = blockIdx.x * blockDim.x + threadIdx.x; e < nnz;
       e += gridDim.x * blockDim.x)
    atomicAdd(&cnt[rows[e]], 1);
}

// Single-block exclusive scan over n counters -> base[0..n], cursor copy.
__global__ __launch_bounds__(256) void k_scan(const int* __restrict__ cnt,
                                              int* __restrict__ base,
                                              int* __restrict__ cursor, int n) {
  __shared__ int sums[256];
  int tid = threadIdx.x;
  int chunk = (n + 255) / 256;
  int s = tid * chunk, e = min(s + chunk, n);
  int local = 0;
  for (int i = s; i < e; ++i) local += cnt[i];
  sums[tid] = local;
  __syncthreads();
  for (int off = 1; off < 256; off <<= 1) {
    int v = (tid >= off) ? sums[tid - off] : 0;
    __syncthreads();
    sums[tid] += v;
    __syncthreads();
  }
  int run = (tid == 0) ? 0 : sums[tid - 1];
  for (int i = s; i < e; ++i) {
    base[i] = run;
    cursor[i] = run;
    run += cnt[i];
  }
  if (tid == 255) base[n] = sums[255];
}

__global__ void k_scatter(const int* __restrict__ rows, int* __restrict__ cursor,
                          int* __restrict__ order, int nnz) {
  for (int e = blockIdx.x * blockDim.x + threadIdx.x; e < nnz;
       e += gridDim.x * blockDim.x) {
    int pos = atomicAdd(&cursor[rows[e]], 1);
    order[pos] = e;
  }
}

// ===========================================================================
// Kernel B: precompute per-input-row intermediates into workspace.
// dmu = mu - mu_history[ifield]; ds2 = (sqrt(var)-sqrt(varh))^2; ms = ds*sqrt(varh)
// One wave per row, lane l handles float4 l.
// ===========================================================================
__global__ __launch_bounds__(256) void k_pre(
    const float* __restrict__ mu, const float* __restrict__ var,
    const float* __restrict__ muh, const float* __restrict__ varh,
    const int* __restrict__ ifield,
    float* __restrict__ dmu, float* __restrict__ ds2, float* __restrict__ ms,
    int n_in) {
  int wave = (int)((blockIdx.x * blockDim.x + threadIdx.x) >> 6);
  int lane = threadIdx.x & 63;
  int nw = (int)((gridDim.x * blockDim.x) >> 6);
  for (int row = wave; row < n_in; row += nw) {
    int f = ifield[row];
    float4 m  = ((const float4*)(mu   + (size_t)row * 256))[lane];
    float4 v  = ((const float4*)(var  + (size_t)row * 256))[lane];
    float4 mh = ((const float4*)(muh  + (size_t)f   * 256))[lane];
    float4 vh = ((const float4*)(varh + (size_t)f   * 256))[lane];
    float4 d, q, p;
    float s, sb, ds;
    s = sqrtf(v.x); sb = sqrtf(vh.x); ds = s - sb; d.x = m.x - mh.x; q.x = ds * ds; p.x = ds * sb;
    s = sqrtf(v.y); sb = sqrtf(vh.y); ds = s - sb; d.y = m.y - mh.y; q.y = ds * ds; p.y = ds * sb;
    s = sqrtf(v.z); sb = sqrtf(vh.z); ds = s - sb; d.z = m.z - mh.z; q.z = ds * ds; p.z = ds * sb;
    s = sqrtf(v.w); sb = sqrtf(vh.w); ds = s - sb; d.w = m.w - mh.w; q.w = ds * ds; p.w = ds * sb;
    ((float4*)(dmu + (size_t)row * 256))[lane] = d;
    ((float4*)(ds2 + (size_t)row * 256))[lane] = q;
    ((float4*)(ms  + (size_t)row * 256))[lane] = p;
  }
}

// ===========================================================================
// Kernel G: per-output-row aggregation over all three CSR'd edge lists.
// One wave per row; lane l owns float4 l of the 256-wide feature row.
// Writes each output row exactly once (self halves + relu(var)+eps fused).
// ===========================================================================
__global__ __launch_bounds__(256) void k_agg(
    const float* __restrict__ mu, const float* __restrict__ var,
    const float* __restrict__ muh, const float* __restrict__ varh,
    const float* __restrict__ dmu, const float* __restrict__ ds2,
    const float* __restrict__ ms,
    const float* __restrict__ adj_vals, const int* __restrict__ adj_cols,
    const float* __restrict__ fadj_vals, const int* __restrict__ fadj_cols,
    const float* __restrict__ madj_vals, const int* __restrict__ madj_cols,
    const int* __restrict__ ffield,
    const int* __restrict__ base_a, const int* __restrict__ ord_a,
    const int* __restrict__ base_f, const int* __restrict__ ord_f,
    const int* __restrict__ base_m, const int* __restrict__ ord_m,
    float* __restrict__ out0, float* __restrict__ out1, int n_out) {
  int r = (int)((blockIdx.x * blockDim.x + threadIdx.x) >> 6);
  int lane = threadIdx.x & 63;
  if (r >= n_out) return;

  float4 am = make_float4(0.f, 0.f, 0.f, 0.f);
  float4 av = make_float4(0.f, 0.f, 0.f, 0.f);

  // ---- adj: am += w*dmu[c]; av += w^2*ds2[c] ----
  {
    int b0 = base_a[r], b1 = base_a[r + 1];
    int p = b0;
    for (; p + 1 < b1; p += 2) {
      int e0 = ord_a[p], e1 = ord_a[p + 1];
      float w0 = adj_vals[e0], w1 = adj_vals[e1];
      int c0 = adj_cols[e0], c1 = adj_cols[e1];
      float4 m0 = ((const float4*)(dmu + (size_t)c0 * 256))[lane];
      float4 v0 = ((const float4*)(ds2 + (size_t)c0 * 256))[lane];
      float4 m1 = ((const float4*)(dmu + (size_t)c1 * 256))[lane];
      float4 v1 = ((const float4*)(ds2 + (size_t)c1 * 256))[lane];
      float q0 = w0 * w0, q1 = w1 * w1;
      am.x += w0 * m0.x + w1 * m1.x; am.y += w0 * m0.y + w1 * m1.y;
      am.z += w0 * m0.z + w1 * m1.z; am.w += w0 * m0.w + w1 * m1.w;
      av.x += q0 * v0.x + q1 * v1.x; av.y += q0 * v0.y + q1 * v1.y;
      av.z += q0 * v0.z + q1 * v1.z; av.w += q0 * v0.w + q1 * v1.w;
    }
    if (p < b1) {
      int e0 = ord_a[p];
      float w0 = adj_vals[e0];
      int c0 = adj_cols[e0];
      float4 m0 = ((const float4*)(dmu + (size_t)c0 * 256))[lane];
      float4 v0 = ((const float4*)(ds2 + (size_t)c0 * 256))[lane];
      float q0 = w0 * w0;
      am.x += w0 * m0.x; am.y += w0 * m0.y; am.z += w0 * m0.z; am.w += w0 * m0.w;
      av.x += q0 * v0.x; av.y += q0 * v0.y; av.z += q0 * v0.z; av.w += q0 * v0.w;
    }
  }

  // ---- fadj: am += w*muh[ffield[c]]; av += w^2*varh[ffield[c]] ----
  {
    int b0 = base_f[r], b1 = base_f[r + 1];
    int p = b0;
    for (; p + 1 < b1; p += 2) {
      int e0 = ord_f[p], e1 = ord_f[p + 1];
      float w0 = fadj_vals[e0], w1 = fadj_vals[e1];
      int f0 = ffield[fadj_cols[e0]], f1 = ffield[fadj_cols[e1]];
      float4 m0 = ((const float4*)(muh  + (size_t)f0 * 256))[lane];
      float4 v0 = ((const float4*)(varh + (size_t)f0 * 256))[lane];
      float4 m1 = ((const float4*)(muh  + (size_t)f1 * 256))[lane];
      float4 v1 = ((const float4*)(varh + (size_t)f1 * 256))[lane];
      float q0 = w0 * w0, q1 = w1 * w1;
      am.x += w0 * m0.x + w1 * m1.x; am.y += w0 * m0.y + w1 * m1.y;
      am.z += w0 * m0.z + w1 * m1.z; am.w += w0 * m0.w + w1 * m1.w;
      av.x += q0 * v0.x + q1 * v1.x; av.y += q0 * v0.y + q1 * v1.y;
      av.z += q0 * v0.z + q1 * v1.z; av.w += q0 * v0.w + q1 * v1.w;
    }
    if (p < b1) {
      int e0 = ord_f[p];
      float w0 = fadj_vals[e0];
      int f0 = ffield[fadj_cols[e0]];
      float4 m0 = ((const float4*)(muh  + (size_t)f0 * 256))[lane];
      float4 v0 = ((const float4*)(varh + (size_t)f0 * 256))[lane];
      float q0 = w0 * w0;
      am.x += w0 * m0.x; am.y += w0 * m0.y; am.z += w0 * m0.z; am.w += w0 * m0.w;
      av.x += q0 * v0.x; av.y += q0 * v0.y; av.z += q0 * v0.z; av.w += q0 * v0.w;
    }
  }

  // ---- madj: av += 2*w*ms[c] ----
  {
    int b0 = base_m[r], b1 = base_m[r + 1];
    int p = b0;
    for (; p + 1 < b1; p += 2) {
      int e0 = ord_m[p], e1 = ord_m[p + 1];
      float w0 = 2.f * madj_vals[e0], w1 = 2.f * madj_vals[e1];
      int c0 = madj_cols[e0], c1 = madj_cols[e1];
      float4 x0 = ((const float4*)(ms + (size_t)c0 * 256))[lane];
      float4 x1 = ((const float4*)(ms + (size_t)c1 * 256))[lane];
      av.x += w0 * x0.x + w1 * x1.x; av.y += w0 * x0.y + w1 * x1.y;
      av.z += w0 * x0.z + w1 * x1.z; av.w += w0 * x0.w + w1 * x1.w;
    }
    if (p < b1) {
      int e0 = ord_m[p];
      float w0 = 2.f * madj_vals[e0];
      int c0 = madj_cols[e0];
      float4 x0 = ((const float4*)(ms + (size_t)c0 * 256))[lane];
      av.x += w0 * x0.x; av.y += w0 * x0.y; av.z += w0 * x0.z; av.w += w0 * x0.w;
    }
  }

  // ---- epilogue: relu+eps on var_neighbour, write both output rows ----
  av.x = fmaxf(av.x, 0.f) + EPS_F;
  av.y = fmaxf(av.y, 0.f) + EPS_F;
  av.z = fmaxf(av.z, 0.f) + EPS_F;
  av.w = fmaxf(av.w, 0.f) + EPS_F;
  float4 msf = ((const float4*)(mu  + (size_t)r * 256))[lane];
  float4 vsf = ((const float4*)(var + (size_t)r * 256))[lane];
  ((float4*)(out0 + (size_t)r * 512))[lane]       = msf;
  ((float4*)(out0 + (size_t)r * 512 + 256))[lane] = am;
  ((float4*)(out1 + (size_t)r * 512))[lane]       = vsf;
  ((float4*)(out1 + (size_t)r * 512 + 256))[lane] = av;
}

// ===========================================================================
// Fallback path (no workspace): round-1 atomic kernels, recompute variant.
// ===========================================================================
__global__ __launch_bounds__(256) void k_init_out(
    const float* __restrict__ mu, const float* __restrict__ var,
    float* __restrict__ out0, float* __restrict__ out1) {
  int r = blockIdx.x;
  int t = threadIdx.x;
  const float4 z = make_float4(0.f, 0.f, 0.f, 0.f);
  if (t < 128) {
    float4* dst = (float4*)(out0 + (size_t)r * 512);
    dst[t] = (t < 64) ? ((const float4*)(mu + (size_t)r * 256))[t] : z;
  } else {
    int u = t - 128;
    float4* dst = (float4*)(out1 + (size_t)r * 512);
    dst[u] = (u < 64) ? ((const float4*)(var + (size_t)r * 256))[u] : z;
  }
}

__global__ __launch_bounds__(256) void k_edge_adj_fb(
    const float* __restrict__ vals, const int* __restrict__ rows,
    const int* __restrict__ cols,
    const float* __restrict__ mu, const float* __restrict__ var,
    const float* __restrict__ muh, const float* __restrict__ varh,
    const int* __restrict__ ifield,
    float* __restrict__ out0, float* __restrict__ out1, int nnz) {
  int wave = (int)((blockIdx.x * blockDim.x + threadIdx.x) >> 6);
  int lane = threadIdx.x & 63;
  int nw = (int)((gridDim.x * blockDim.x) >> 6);
  for (int e = wave; e < nnz; e += nw) {
    float w = vals[e];
    int r = rows[e];
    int c = cols[e];
    int f = ifield[c];
    float4 m  = ((const float4*)(mu   + (size_t)c * 256))[lane];
    float4 v  = ((const float4*)(var  + (size_t)c * 256))[lane];
    float4 mh = ((const float4*)(muh  + (size_t)f * 256))[lane];
    float4 vh = ((const float4*)(varh + (size_t)f * 256))[lane];
    float4 xm, xv;
    float ds;
    xm.x = m.x - mh.x; ds = sqrtf(v.x) - sqrtf(vh.x); xv.x = ds * ds;
    xm.y = m.y - mh.y; ds = sqrtf(v.y) - sqrtf(vh.y); xv.y = ds * ds;
    xm.z = m.z - mh.z; ds = sqrtf(v.z) - sqrtf(vh.z); xv.z = ds * ds;
    xm.w = m.w - mh.w; ds = sqrtf(v.w) - sqrtf(vh.w); xv.w = ds * ds;
    float w2 = w * w;
    float* om = out0 + (size_t)r * 512 + 256 + lane * 4;
    float* ov = out1 + (size_t)r * 512 + 256 + lane * 4;
    atomicAdd(om + 0, w * xm.x); atomicAdd(om + 1, w * xm.y);
    atomicAdd(om + 2, w * xm.z); atomicAdd(om + 3, w * xm.w);
    atomicAdd(ov + 0, w2 * xv.x); atomicAdd(ov + 1, w2 * xv.y);
    atomicAdd(ov + 2, w2 * xv.z); atomicAdd(ov + 3, w2 * xv.w);
  }
}

__global__ __launch_bounds__(256) void k_edge_fadj_fb(
    const float* __restrict__ vals, const int* __restrict__ rows,
    const int* __restrict__ cols,
    const float* __restrict__ muh, const float* __restrict__ varh,
    const int* __restrict__ ffield,
    float* __restrict__ out0, float* __restrict__ out1, int nnz) {
  int wave = (int)((blockIdx.x * blockDim.x + threadIdx.x) >> 6);
  int lane = threadIdx.x & 63;
  int nw = (int)((gridDim.x * blockDim.x) >> 6);
  for (int e = wave; e < nnz; e += nw) {
    float w = vals[e];
    int r = rows[e];
    int f = ffield[cols[e]];
    float4 mb = ((const float4*)(muh  + (size_t)f * 256))[lane];
    float4 vb = ((const float4*)(varh + (size_t)f * 256))[lane];
    float w2 = w * w;
    float* om = out0 + (size_t)r * 512 + 256 + lane * 4;
    float* ov = out1 + (size_t)r * 512 + 256 + lane * 4;
    atomicAdd(om + 0, w * mb.x); atomicAdd(om + 1, w * mb.y);
    atomicAdd(om + 2, w * mb.z); atomicAdd(om + 3, w * mb.w);
    atomicAdd(ov + 0, w2 * vb.x); atomicAdd(ov + 1, w2 * vb.y);
    atomicAdd(ov + 2, w2 * vb.z); atomicAdd(ov + 3, w2 * vb.w);
  }
}

__global__ __launch_bounds__(256) void k_edge_madj_fb(
    const float* __restrict__ vals, const int* __restrict__ rows,
    const int* __restrict__ cols,
    const float* __restrict__ var, const float* __restrict__ varh,
    const int* __restrict__ ifield,
    float* __restrict__ out1, int nnz) {
  int wave = (int)((blockIdx.x * blockDim.x + threadIdx.x) >> 6);
  int lane = threadIdx.x & 63;
  int nw = (int)((gridDim.x * blockDim.x) >> 6);
  for (int e = wave; e < nnz; e += nw) {
    float w = 2.0f * vals[e];
    int r = rows[e];
    int c = cols[e];
    int f = ifield[c];
    float4 v  = ((const float4*)(var  + (size_t)c * 256))[lane];
    float4 vh = ((const float4*)(varh + (size_t)f * 256))[lane];
    float4 x;
    float sb;
    sb = sqrtf(vh.x); x.x = (sqrtf(v.x) - sb) * sb;
    sb = sqrtf(vh.y); x.y = (sqrtf(v.y) - sb) * sb;
    sb = sqrtf(vh.z); x.z = (sqrtf(v.z) - sb) * sb;
    sb = sqrtf(vh.w); x.w = (sqrtf(v.w) - sb) * sb;
    float* ov = out1 + (size_t)r * 512 + 256 + lane * 4;
    atomicAdd(ov + 0, w * x.x); atomicAdd(ov + 1, w * x.y);
    atomicAdd(ov + 2, w * x.z); atomicAdd(ov + 3, w * x.w);
  }
}

__global__ __launch_bounds__(256) void k_final(float* __restrict__ out1, int n_out) {
  int total = n_out * 64;
  for (int i = blockIdx.x * blockDim.x + threadIdx.x; i < total;
       i += gridDim.x * blockDim.x) {
    int r = i >> 6;
    int q = i & 63;
    float4* p = (float4*)(out1 + (size_t)r * 512 + 256) + q;
    float4 v = *p;
    v.x = fmaxf(v.x, 0.f) + EPS_F;
    v.y = fmaxf(v.y, 0.f) + EPS_F;
    v.z = fmaxf(v.z, 0.f) + EPS_F;
    v.w = fmaxf(v.w, 0.f) + EPS_F;
    *p = v;
  }
}

// ===========================================================================
extern "C" void kernel_launch(void* const* d_in, const int* in_sizes, int n_in_args,
                              void* d_out, int out_size, void* d_ws, size_t ws_size,
                              hipStream_t stream) {
  const float* mu        = (const float*)d_in[0];
  const float* var       = (const float*)d_in[1];
  const float* muh       = (const float*)d_in[2];
  const float* varh      = (const float*)d_in[3];
  const float* adj_vals  = (const float*)d_in[4];
  const float* fadj_vals = (const float*)d_in[5];
  const float* madj_vals = (const float*)d_in[6];
  const int* adj_rows    = (const int*)d_in[7];
  const int* adj_cols    = (const int*)d_in[8];
  const int* fadj_rows   = (const int*)d_in[9];
  const int* fadj_cols   = (const int*)d_in[10];
  const int* madj_rows   = (const int*)d_in[11];
  const int* madj_cols   = (const int*)d_in[12];
  const int* ifield      = (const int*)d_in[13];
  const int* ffield      = (const int*)d_in[14];

  const int n_out = out_size / 1024;   // two outputs, 512 cols each
  const int n_in  = in_sizes[0] / 256;
  const int nnz   = in_sizes[4];

  float* out0 = (float*)d_out;
  float* out1 = out0 + (size_t)n_out * 512;

  // Workspace layout: 3 float arrays (dmu, ds2, ms), then per-matrix int arrays.
  const size_t fsz = (size_t)n_in * 256;
  const size_t int_per_mat = (size_t)n_out /*cnt*/ + (size_t)(n_out + 1) /*base*/ +
                             (size_t)n_out /*cursor*/ + (size_t)nnz /*order*/;
  const size_t need = (3 * fsz) * sizeof(float) + 3 * int_per_mat * sizeof(int);

  if (ws_size >= need) {
    float* dmu = (float*)d_ws;
    float* ds2 = dmu + fsz;
    float* ms  = ds2 + fsz;
    int* ibase = (int*)(ms + fsz);
    int* cnt_a = ibase;                 int* cnt_f = cnt_a + int_per_mat;   int* cnt_m = cnt_f + int_per_mat;
    int* base_a = cnt_a + n_out;        int* base_f = cnt_f + n_out;        int* base_m = cnt_m + n_out;
    int* cur_a  = base_a + n_out + 1;   int* cur_f  = base_f + n_out + 1;   int* cur_m  = base_m + n_out + 1;
    int* ord_a  = cur_a + n_out;        int* ord_f  = cur_f + n_out;        int* ord_m  = cur_m + n_out;

    // CSR build for the three edge lists.
    k_zero_i32<<<256, 256, 0, stream>>>(cnt_a, n_out);
    k_zero_i32<<<256, 256, 0, stream>>>(cnt_f, n_out);
    k_zero_i32<<<256, 256, 0, stream>>>(cnt_m, n_out);
    k_count<<<1024, 256, 0, stream>>>(adj_rows,  cnt_a, nnz);
    k_count<<<1024, 256, 0, stream>>>(fadj_rows, cnt_f, nnz);
    k_count<<<1024, 256, 0, stream>>>(madj_rows, cnt_m, nnz);
    k_scan<<<1, 256, 0, stream>>>(cnt_a, base_a, cur_a, n_out);
    k_scan<<<1, 256, 0, stream>>>(cnt_f, base_f, cur_f, n_out);
    k_scan<<<1, 256, 0, stream>>>(cnt_m, base_m, cur_m, n_out);
    k_scatter<<<1024, 256, 0, stream>>>(adj_rows,  cur_a, ord_a, nnz);
    k_scatter<<<1024, 256, 0, stream>>>(fadj_rows, cur_f, ord_f, nnz);
    k_scatter<<<1024, 256, 0, stream>>>(madj_rows, cur_m, ord_m, nnz);

    // Precompute intermediates.
    k_pre<<<4096, 256, 0, stream>>>(mu, var, muh, varh, ifield, dmu, ds2, ms, n_in);

    // One wave per output row aggregates everything, writes once.
    int blocks = (n_out * 64 + 255) / 256;
    k_agg<<<blocks, 256, 0, stream>>>(mu, var, muh, varh, dmu, ds2, ms,
                                      adj_vals, adj_cols, fadj_vals, fadj_cols,
                                      madj_vals, madj_cols, ffield,
                                      base_a, ord_a, base_f, ord_f, base_m, ord_m,
                                      out0, out1, n_out);
  } else {
    // Fallback: atomic scatter path (no workspace).
    k_init_out<<<n_out, 256, 0, stream>>>(mu, var, out0, out1);
    k_edge_adj_fb<<<4096, 256, 0, stream>>>(adj_vals, adj_rows, adj_cols,
                                            mu, var, muh, varh, ifield, out0, out1, nnz);
    k_edge_madj_fb<<<4096, 256, 0, stream>>>(madj_vals, madj_rows, madj_cols,
                                             var, varh, ifield, out1, nnz);
    k_edge_fadj_fb<<<4096, 256, 0, stream>>>(fadj_vals, fadj_rows, fadj_cols,
                                             muh, varh, ffield, out0, out1, nnz);
    k_final<<<4096, 256, 0, stream>>>(out1, n_out);
  }
}

// Round 3
// 324.783 us; speedup vs baseline: 13.6830x; 1.5469x over previous
//
#include <hip/hip_runtime.h>

#define EPS_F 1e-10f

typedef unsigned int u32;

// bf16 pack (RTN) / unpack helpers -------------------------------------------
__device__ __forceinline__ u32 bf16pair(float lo, float hi) {
  u32 a = __float_as_uint(lo);
  u32 b = __float_as_uint(hi);
  a = a + 0x7FFFu + ((a >> 16) & 1u);
  b = b + 0x7FFFu + ((b >> 16) & 1u);
  return (a >> 16) | (b & 0xFFFF0000u);
}
__device__ __forceinline__ float bf_lo(u32 u) { return __uint_as_float(u << 16); }
__device__ __forceinline__ float bf_hi(u32 u) { return __uint_as_float(u & 0xFFFF0000u); }

// ===========================================================================
// CSR build (all 3 matrices per kernel).
// ===========================================================================
__global__ __launch_bounds__(256) void k_count3(
    const int* __restrict__ ra, const int* __restrict__ rf,
    const int* __restrict__ rm, int* __restrict__ cnt, int nnz, int n_out) {
  int total = 3 * nnz;
  for (int i = blockIdx.x * blockDim.x + threadIdx.x; i < total;
       i += gridDim.x * blockDim.x) {
    int m = (i >= nnz) + (i >= 2 * nnz);
    int e = i - m * nnz;
    const int* rp = (m == 0) ? ra : (m == 1) ? rf : rm;
    atomicAdd(&cnt[m * n_out + rp[e]], 1);
  }
}

// blockIdx.x = matrix index (3 blocks).
__global__ __launch_bounds__(256) void k_scan3(const int* __restrict__ cnt_all,
                                               int* __restrict__ base_all,
                                               int* __restrict__ cur_all, int n) {
  const int* cnt = cnt_all + blockIdx.x * n;
  int* base = base_all + blockIdx.x * (n + 1);
  int* cur = cur_all + blockIdx.x * n;
  __shared__ int sums[256];
  int tid = threadIdx.x;
  int chunk = (n + 255) / 256;
  int s = tid * chunk, e = min(s + chunk, n);
  int local = 0;
  for (int i = s; i < e; ++i) local += cnt[i];
  sums[tid] = local;
  __syncthreads();
  for (int off = 1; off < 256; off <<= 1) {
    int v = (tid >= off) ? sums[tid - off] : 0;
    __syncthreads();
    sums[tid] += v;
    __syncthreads();
  }
  int run = (tid == 0) ? 0 : sums[tid - 1];
  for (int i = s; i < e; ++i) {
    base[i] = run;
    cur[i] = run;
    run += cnt[i];
  }
  if (tid == 255) base[n] = sums[255];
}

// Scatter edges into CSR order as (col_or_field, val_bits) pairs.
// fadj: col pre-resolved through ffield. madj: val pre-scaled by 2.
__global__ __launch_bounds__(256) void k_scatter3(
    const int* __restrict__ ra, const int* __restrict__ ca, const float* __restrict__ va,
    const int* __restrict__ rf, const int* __restrict__ cf, const float* __restrict__ vf,
    const int* __restrict__ rm, const int* __restrict__ cm, const float* __restrict__ vm,
    const int* __restrict__ ffield,
    int* __restrict__ cur_all, uint2* __restrict__ ord, int nnz, int n_out) {
  int total = 3 * nnz;
  for (int i = blockIdx.x * blockDim.x + threadIdx.x; i < total;
       i += gridDim.x * blockDim.x) {
    int m = (i >= nnz) + (i >= 2 * nnz);
    int e = i - m * nnz;
    const int* rp = (m == 0) ? ra : (m == 1) ? rf : rm;
    const int* cp = (m == 0) ? ca : (m == 1) ? cf : cm;
    const float* vp = (m == 0) ? va : (m == 1) ? vf : vm;
    int r = rp[e];
    int c = cp[e];
    float w = vp[e];
    if (m == 1) c = ffield[c];
    if (m == 2) w = 2.0f * w;
    int pos = atomicAdd(&cur_all[m * n_out + r], 1);
    ord[(size_t)m * nnz + pos] = make_uint2((u32)c, __float_as_uint(w));
  }
}

// ===========================================================================
// k_pre: per-input-row intermediates, bf16-compressed.
// A[row] : 512 bf16 = interleave per lane [dmu x4, ds2 x4] (1 KB/row)
// M[row] : 256 bf16 = msigma (512 B/row)
// ===========================================================================
__global__ __launch_bounds__(256) void k_pre(
    const float* __restrict__ mu, const float* __restrict__ var,
    const float* __restrict__ muh, const float* __restrict__ varh,
    const int* __restrict__ ifield,
    u32* __restrict__ A, u32* __restrict__ M, int n_in) {
  int wave = (int)((blockIdx.x * blockDim.x + threadIdx.x) >> 6);
  int lane = threadIdx.x & 63;
  int nw = (int)((gridDim.x * blockDim.x) >> 6);
  for (int row = wave; row < n_in; row += nw) {
    int f = ifield[row];
    float4 m  = ((const float4*)(mu   + (size_t)row * 256))[lane];
    float4 v  = ((const float4*)(var  + (size_t)row * 256))[lane];
    float4 mh = ((const float4*)(muh  + (size_t)f   * 256))[lane];
    float4 vh = ((const float4*)(varh + (size_t)f   * 256))[lane];
    float4 d, q, p;
    float s, sb, ds;
    s = sqrtf(v.x); sb = sqrtf(vh.x); ds = s - sb; d.x = m.x - mh.x; q.x = ds * ds; p.x = ds * sb;
    s = sqrtf(v.y); sb = sqrtf(vh.y); ds = s - sb; d.y = m.y - mh.y; q.y = ds * ds; p.y = ds * sb;
    s = sqrtf(v.z); sb = sqrtf(vh.z); ds = s - sb; d.z = m.z - mh.z; q.z = ds * ds; p.z = ds * sb;
    s = sqrtf(v.w); sb = sqrtf(vh.w); ds = s - sb; d.w = m.w - mh.w; q.w = ds * ds; p.w = ds * sb;
    uint4 au;
    au.x = bf16pair(d.x, d.y);
    au.y = bf16pair(d.z, d.w);
    au.z = bf16pair(q.x, q.y);
    au.w = bf16pair(q.z, q.w);
    ((uint4*)(A + (size_t)row * 256))[lane] = au;
    uint2 mu2;
    mu2.x = bf16pair(p.x, p.y);
    mu2.y = bf16pair(p.z, p.w);
    ((uint2*)(M + (size_t)row * 128))[lane] = mu2;
  }
}

// ===========================================================================
// k_agg: one wave per output row; accumulate all three edge lists in
// registers; write each output row exactly once, relu+eps fused.
// ===========================================================================
__global__ __launch_bounds__(256) void k_agg(
    const float* __restrict__ mu, const float* __restrict__ var,
    const float* __restrict__ muh, const float* __restrict__ varh,
    const u32* __restrict__ A, const u32* __restrict__ M,
    const int* __restrict__ base_all, const uint2* __restrict__ ord,
    float* __restrict__ out0, float* __restrict__ out1, int n_out, int nnz) {
  int r = (int)((blockIdx.x * blockDim.x + threadIdx.x) >> 6);
  int lane = threadIdx.x & 63;
  if (r >= n_out) return;

  float4 am = make_float4(0.f, 0.f, 0.f, 0.f);
  float4 av = make_float4(0.f, 0.f, 0.f, 0.f);

  // ---- adj: am += w*dmu[c]; av += w^2*ds2[c]  (bf16 interleaved in A) ----
  {
    const int* base = base_all;
    const uint2* o = ord;
    int b0 = base[r], b1 = base[r + 1];
    int p = b0;
    for (; p + 1 < b1; p += 2) {
      uint2 cv0 = o[p], cv1 = o[p + 1];
      float w0 = __uint_as_float(cv0.y), w1 = __uint_as_float(cv1.y);
      uint4 u0 = ((const uint4*)(A + (size_t)cv0.x * 256))[lane];
      uint4 u1 = ((const uint4*)(A + (size_t)cv1.x * 256))[lane];
      float q0 = w0 * w0, q1 = w1 * w1;
      am.x += w0 * bf_lo(u0.x) + w1 * bf_lo(u1.x);
      am.y += w0 * bf_hi(u0.x) + w1 * bf_hi(u1.x);
      am.z += w0 * bf_lo(u0.y) + w1 * bf_lo(u1.y);
      am.w += w0 * bf_hi(u0.y) + w1 * bf_hi(u1.y);
      av.x += q0 * bf_lo(u0.z) + q1 * bf_lo(u1.z);
      av.y += q0 * bf_hi(u0.z) + q1 * bf_hi(u1.z);
      av.z += q0 * bf_lo(u0.w) + q1 * bf_lo(u1.w);
      av.w += q0 * bf_hi(u0.w) + q1 * bf_hi(u1.w);
    }
    if (p < b1) {
      uint2 cv0 = o[p];
      float w0 = __uint_as_float(cv0.y);
      uint4 u0 = ((const uint4*)(A + (size_t)cv0.x * 256))[lane];
      float q0 = w0 * w0;
      am.x += w0 * bf_lo(u0.x); am.y += w0 * bf_hi(u0.x);
      am.z += w0 * bf_lo(u0.y); am.w += w0 * bf_hi(u0.y);
      av.x += q0 * bf_lo(u0.z); av.y += q0 * bf_hi(u0.z);
      av.z += q0 * bf_lo(u0.w); av.w += q0 * bf_hi(u0.w);
    }
  }

  // ---- fadj: am += w*muh[f]; av += w^2*varh[f]  (f pre-resolved, f32) ----
  {
    const int* base = base_all + (n_out + 1);
    const uint2* o = ord + (size_t)nnz;
    int b0 = base[r], b1 = base[r + 1];
    int p = b0;
    for (; p + 1 < b1; p += 2) {
      uint2 cv0 = o[p], cv1 = o[p + 1];
      float w0 = __uint_as_float(cv0.y), w1 = __uint_as_float(cv1.y);
      float4 m0 = ((const float4*)(muh  + (size_t)cv0.x * 256))[lane];
      float4 v0 = ((const float4*)(varh + (size_t)cv0.x * 256))[lane];
      float4 m1 = ((const float4*)(muh  + (size_t)cv1.x * 256))[lane];
      float4 v1 = ((const float4*)(varh + (size_t)cv1.x * 256))[lane];
      float q0 = w0 * w0, q1 = w1 * w1;
      am.x += w0 * m0.x + w1 * m1.x; am.y += w0 * m0.y + w1 * m1.y;
      am.z += w0 * m0.z + w1 * m1.z; am.w += w0 * m0.w + w1 * m1.w;
      av.x += q0 * v0.x + q1 * v1.x; av.y += q0 * v0.y + q1 * v1.y;
      av.z += q0 * v0.z + q1 * v1.z; av.w += q0 * v0.w + q1 * v1.w;
    }
    if (p < b1) {
      uint2 cv0 = o[p];
      float w0 = __uint_as_float(cv0.y);
      float4 m0 = ((const float4*)(muh  + (size_t)cv0.x * 256))[lane];
      float4 v0 = ((const float4*)(varh + (size_t)cv0.x * 256))[lane];
      float q0 = w0 * w0;
      am.x += w0 * m0.x; am.y += w0 * m0.y; am.z += w0 * m0.z; am.w += w0 * m0.w;
      av.x += q0 * v0.x; av.y += q0 * v0.y; av.z += q0 * v0.z; av.w += q0 * v0.w;
    }
  }

  // ---- madj: av += (2w)*ms[c]  (scale folded at scatter; bf16 in M) ----
  {
    const int* base = base_all + 2 * (n_out + 1);
    const uint2* o = ord + 2 * (size_t)nnz;
    int b0 = base[r], b1 = base[r + 1];
    int p = b0;
    for (; p + 1 < b1; p += 2) {
      uint2 cv0 = o[p], cv1 = o[p + 1];
      float w0 = __uint_as_float(cv0.y), w1 = __uint_as_float(cv1.y);
      uint2 x0 = ((const uint2*)(M + (size_t)cv0.x * 128))[lane];
      uint2 x1 = ((const uint2*)(M + (size_t)cv1.x * 128))[lane];
      av.x += w0 * bf_lo(x0.x) + w1 * bf_lo(x1.x);
      av.y += w0 * bf_hi(x0.x) + w1 * bf_hi(x1.x);
      av.z += w0 * bf_lo(x0.y) + w1 * bf_lo(x1.y);
      av.w += w0 * bf_hi(x0.y) + w1 * bf_hi(x1.y);
    }
    if (p < b1) {
      uint2 cv0 = o[p];
      float w0 = __uint_as_float(cv0.y);
      uint2 x0 = ((const uint2*)(M + (size_t)cv0.x * 128))[lane];
      av.x += w0 * bf_lo(x0.x); av.y += w0 * bf_hi(x0.x);
      av.z += w0 * bf_lo(x0.y); av.w += w0 * bf_hi(x0.y);
    }
  }

  // ---- epilogue ----
  av.x = fmaxf(av.x, 0.f) + EPS_F;
  av.y = fmaxf(av.y, 0.f) + EPS_F;
  av.z = fmaxf(av.z, 0.f) + EPS_F;
  av.w = fmaxf(av.w, 0.f) + EPS_F;
  float4 msf = ((const float4*)(mu  + (size_t)r * 256))[lane];
  float4 vsf = ((const float4*)(var + (size_t)r * 256))[lane];
  ((float4*)(out0 + (size_t)r * 512))[lane]       = msf;
  ((float4*)(out0 + (size_t)r * 512 + 256))[lane] = am;
  ((float4*)(out1 + (size_t)r * 512))[lane]       = vsf;
  ((float4*)(out1 + (size_t)r * 512 + 256))[lane] = av;
}

// ===========================================================================
// Fallback (no workspace): atomic scatter path, recompute variant.
// ===========================================================================
__global__ __launch_bounds__(256) void k_init_out(
    const float* __restrict__ mu, const float* __restrict__ var,
    float* __restrict__ out0, float* __restrict__ out1) {
  int r = blockIdx.x;
  int t = threadIdx.x;
  const float4 z = make_float4(0.f, 0.f, 0.f, 0.f);
  if (t < 128) {
    float4* dst = (float4*)(out0 + (size_t)r * 512);
    dst[t] = (t < 64) ? ((const float4*)(mu + (size_t)r * 256))[t] : z;
  } else {
    int u = t - 128;
    float4* dst = (float4*)(out1 + (size_t)r * 512);
    dst[u] = (u < 64) ? ((const float4*)(var + (size_t)r * 256))[u] : z;
  }
}

__global__ __launch_bounds__(256) void k_edge_adj_fb(
    const float* __restrict__ vals, const int* __restrict__ rows,
    const int* __restrict__ cols,
    const float* __restrict__ mu, const float* __restrict__ var,
    const float* __restrict__ muh, const float* __restrict__ varh,
    const int* __restrict__ ifield,
    float* __restrict__ out0, float* __restrict__ out1, int nnz) {
  int wave = (int)((blockIdx.x * blockDim.x + threadIdx.x) >> 6);
  int lane = threadIdx.x & 63;
  int nw = (int)((gridDim.x * blockDim.x) >> 6);
  for (int e = wave; e < nnz; e += nw) {
    float w = vals[e];
    int r = rows[e];
    int c = cols[e];
    int f = ifield[c];
    float4 m  = ((const float4*)(mu   + (size_t)c * 256))[lane];
    float4 v  = ((const float4*)(var  + (size_t)c * 256))[lane];
    float4 mh = ((const float4*)(muh  + (size_t)f * 256))[lane];
    float4 vh = ((const float4*)(varh + (size_t)f * 256))[lane];
    float4 xm, xv;
    float ds;
    xm.x = m.x - mh.x; ds = sqrtf(v.x) - sqrtf(vh.x); xv.x = ds * ds;
    xm.y = m.y - mh.y; ds = sqrtf(v.y) - sqrtf(vh.y); xv.y = ds * ds;
    xm.z = m.z - mh.z; ds = sqrtf(v.z) - sqrtf(vh.z); xv.z = ds * ds;
    xm.w = m.w - mh.w; ds = sqrtf(v.w) - sqrtf(vh.w); xv.w = ds * ds;
    float w2 = w * w;
    float* om = out0 + (size_t)r * 512 + 256 + lane * 4;
    float* ov = out1 + (size_t)r * 512 + 256 + lane * 4;
    atomicAdd(om + 0, w * xm.x); atomicAdd(om + 1, w * xm.y);
    atomicAdd(om + 2, w * xm.z); atomicAdd(om + 3, w * xm.w);
    atomicAdd(ov + 0, w2 * xv.x); atomicAdd(ov + 1, w2 * xv.y);
    atomicAdd(ov + 2, w2 * xv.z); atomicAdd(ov + 3, w2 * xv.w);
  }
}

__global__ __launch_bounds__(256) void k_edge_fadj_fb(
    const float* __restrict__ vals, const int* __restrict__ rows,
    const int* __restrict__ cols,
    const float* __restrict__ muh, const float* __restrict__ varh,
    const int* __restrict__ ffield,
    float* __restrict__ out0, float* __restrict__ out1, int nnz) {
  int wave = (int)((blockIdx.x * blockDim.x + threadIdx.x) >> 6);
  int lane = threadIdx.x & 63;
  int nw = (int)((gridDim.x * blockDim.x) >> 6);
  for (int e = wave; e < nnz; e += nw) {
    float w = vals[e];
    int r = rows[e];
    int f = ffield[cols[e]];
    float4 mb = ((const float4*)(muh  + (size_t)f * 256))[lane];
    float4 vb = ((const float4*)(varh + (size_t)f * 256))[lane];
    float w2 = w * w;
    float* om = out0 + (size_t)r * 512 + 256 + lane * 4;
    float* ov = out1 + (size_t)r * 512 + 256 + lane * 4;
    atomicAdd(om + 0, w * mb.x); atomicAdd(om + 1, w * mb.y);
    atomicAdd(om + 2, w * mb.z); atomicAdd(om + 3, w * mb.w);
    atomicAdd(ov + 0, w2 * vb.x); atomicAdd(ov + 1, w2 * vb.y);
    atomicAdd(ov + 2, w2 * vb.z); atomicAdd(ov + 3, w2 * vb.w);
  }
}

__global__ __launch_bounds__(256) void k_edge_madj_fb(
    const float* __restrict__ vals, const int* __restrict__ rows,
    const int* __restrict__ cols,
    const float* __restrict__ var, const float* __restrict__ varh,
    const int* __restrict__ ifield,
    float* __restrict__ out1, int nnz) {
  int wave = (int)((blockIdx.x * blockDim.x + threadIdx.x) >> 6);
  int lane = threadIdx.x & 63;
  int nw = (int)((gridDim.x * blockDim.x) >> 6);
  for (int e = wave; e < nnz; e += nw) {
    float w = 2.0f * vals[e];
    int r = rows[e];
    int c = cols[e];
    int f = ifield[c];
    float4 v  = ((const float4*)(var  + (size_t)c * 256))[lane];
    float4 vh = ((const float4*)(varh + (size_t)f * 256))[lane];
    float4 x;
    float sb;
    sb = sqrtf(vh.x); x.x = (sqrtf(v.x) - sb) * sb;
    sb = sqrtf(vh.y); x.y = (sqrtf(v.y) - sb) * sb;
    sb = sqrtf(vh.z); x.z = (sqrtf(v.z) - sb) * sb;
    sb = sqrtf(vh.w); x.w = (sqrtf(v.w) - sb) * sb;
    float* ov = out1 + (size_t)r * 512 + 256 + lane * 4;
    atomicAdd(ov + 0, w * x.x); atomicAdd(ov + 1, w * x.y);
    atomicAdd(ov + 2, w * x.z); atomicAdd(ov + 3, w * x.w);
  }
}

__global__ __launch_bounds__(256) void k_final(float* __restrict__ out1, int n_out) {
  int total = n_out * 64;
  for (int i = blockIdx.x * blockDim.x + threadIdx.x; i < total;
       i += gridDim.x * blockDim.x) {
    int r = i >> 6;
    int q = i & 63;
    float4* p = (float4*)(out1 + (size_t)r * 512 + 256) + q;
    float4 v = *p;
    v.x = fmaxf(v.x, 0.f) + EPS_F;
    v.y = fmaxf(v.y, 0.f) + EPS_F;
    v.z = fmaxf(v.z, 0.f) + EPS_F;
    v.w = fmaxf(v.w, 0.f) + EPS_F;
    *p = v;
  }
}

// ===========================================================================
extern "C" void kernel_launch(void* const* d_in, const int* in_sizes, int n_in_args,
                              void* d_out, int out_size, void* d_ws, size_t ws_size,
                              hipStream_t stream) {
  const float* mu        = (const float*)d_in[0];
  const float* var       = (const float*)d_in[1];
  const float* muh       = (const float*)d_in[2];
  const float* varh      = (const float*)d_in[3];
  const float* adj_vals  = (const float*)d_in[4];
  const float* fadj_vals = (const float*)d_in[5];
  const float* madj_vals = (const float*)d_in[6];
  const int* adj_rows    = (const int*)d_in[7];
  const int* adj_cols    = (const int*)d_in[8];
  const int* fadj_rows   = (const int*)d_in[9];
  const int* fadj_cols   = (const int*)d_in[10];
  const int* madj_rows   = (const int*)d_in[11];
  const int* madj_cols   = (const int*)d_in[12];
  const int* ifield      = (const int*)d_in[13];
  const int* ffield      = (const int*)d_in[14];

  const int n_out = out_size / 1024;   // two outputs, 512 cols each
  const int n_in  = in_sizes[0] / 256;
  const int nnz   = in_sizes[4];

  float* out0 = (float*)d_out;
  float* out1 = out0 + (size_t)n_out * 512;

  // Workspace layout (u32 units):
  //  A    : n_in*256  (interleaved bf16 dmu/ds2, 1 KB/row)
  //  M    : n_in*128  (bf16 msigma, 512 B/row)
  //  ord  : 3*nnz*2   (uint2 (col,val) per edge, CSR order) [8-B aligned]
  //  cnt  : 3*n_out
  //  base : 3*(n_out+1)
  //  cur  : 3*n_out
  const size_t uA = (size_t)n_in * 256;
  const size_t uM = (size_t)n_in * 128;
  const size_t uOrd = (size_t)3 * nnz * 2;
  const size_t uCnt = (size_t)3 * n_out;
  const size_t uBase = (size_t)3 * (n_out + 1);
  const size_t need = (uA + uM + uOrd + uCnt + uBase + uCnt) * sizeof(u32);

  if (ws_size >= need) {
    u32* A = (u32*)d_ws;
    u32* M = A + uA;
    uint2* ord = (uint2*)(M + uM);
    int* cnt  = (int*)(M + uM + uOrd);
    int* base = cnt + uCnt;
    int* cur  = base + uBase;

    hipMemsetAsync(cnt, 0, uCnt * sizeof(int), stream);
    k_count3<<<1024, 256, 0, stream>>>(adj_rows, fadj_rows, madj_rows, cnt, nnz, n_out);
    k_scan3<<<3, 256, 0, stream>>>(cnt, base, cur, n_out);
    k_scatter3<<<1024, 256, 0, stream>>>(adj_rows, adj_cols, adj_vals,
                                         fadj_rows, fadj_cols, fadj_vals,
                                         madj_rows, madj_cols, madj_vals,
                                         ffield, cur, ord, nnz, n_out);
    k_pre<<<4096, 256, 0, stream>>>(mu, var, muh, varh, ifield, A, M, n_in);
    int blocks = (n_out * 64 + 255) / 256;
    k_agg<<<blocks, 256, 0, stream>>>(mu, var, muh, varh, A, M, base, ord,
                                      out0, out1, n_out, nnz);
  } else {
    k_init_out<<<n_out, 256, 0, stream>>>(mu, var, out0, out1);
    k_edge_adj_fb<<<4096, 256, 0, stream>>>(adj_vals, adj_rows, adj_cols,
                                            mu, var, muh, varh, ifield, out0, out1, nnz);
    k_edge_madj_fb<<<4096, 256, 0, stream>>>(madj_vals, madj_rows, madj_cols,
                                             var, varh, ifield, out1, nnz);
    k_edge_fadj_fb<<<4096, 256, 0, stream>>>(fadj_vals, fadj_rows, fadj_cols,
                                             muh, varh, ffield, out0, out1, nnz);
    k_final<<<4096, 256, 0, stream>>>(out1, n_out);
  }
}

// Round 4
// 313.951 us; speedup vs baseline: 14.1551x; 1.0345x over previous
//
#include <hip/hip_runtime.h>

#define EPS_F 1e-10f

typedef unsigned int u32;

// bf16 pack (RTN) / unpack helpers -------------------------------------------
__device__ __forceinline__ u32 bf16pair(float lo, float hi) {
  u32 a = __float_as_uint(lo);
  u32 b = __float_as_uint(hi);
  a = a + 0x7FFFu + ((a >> 16) & 1u);
  b = b + 0x7FFFu + ((b >> 16) & 1u);
  return (a >> 16) | (b & 0xFFFF0000u);
}
__device__ __forceinline__ float bf_lo(u32 u) { return __uint_as_float(u << 16); }
__device__ __forceinline__ float bf_hi(u32 u) { return __uint_as_float(u & 0xFFFF0000u); }

// ===========================================================================
// k_pre: fused (a) COO row counting for all 3 matrices, (b) per-input-row
// intermediates A/M (bf16), (c) [tier1] pre-gathered fadj source FB (bf16).
// A[row]  : 256 u32 = per lane [dmu x4 | ds2 x4]           (1 KB/row)
// M[row]  : 128 u32 = per lane [ms x4]                     (512 B/row)
// FB[col] : 256 u32 = per lane [mu_bar x4 | var_bar x4]    (1 KB/row)
// ===========================================================================
template <bool WITH_FB>
__global__ __launch_bounds__(256) void k_pre(
    const float* __restrict__ mu, const float* __restrict__ var,
    const float* __restrict__ muh, const float* __restrict__ varh,
    const int* __restrict__ ifield, const int* __restrict__ ffield,
    const int* __restrict__ ra, const int* __restrict__ rf,
    const int* __restrict__ rm, int* __restrict__ cnt,
    u32* __restrict__ A, u32* __restrict__ M, u32* __restrict__ FB,
    int n_in, int n_full, int n_out, int nnz) {
  int tid = blockIdx.x * blockDim.x + threadIdx.x;
  int nth = gridDim.x * blockDim.x;

  // --- (a) edge counting, grid-strided over 3*nnz ---
  int total = 3 * nnz;
  for (int i = tid; i < total; i += nth) {
    int m = (i >= nnz) + (i >= 2 * nnz);
    int e = i - m * nnz;
    const int* rp = (m == 0) ? ra : (m == 1) ? rf : rm;
    atomicAdd(&cnt[m * n_out + rp[e]], 1);
  }

  // --- (b)+(c) wave-per-row ---
  int wave = tid >> 6;
  int lane = tid & 63;
  int nw = nth >> 6;
  int nr = WITH_FB ? max(n_in, n_full) : n_in;
  for (int row = wave; row < nr; row += nw) {
    if (row < n_in) {
      int f = ifield[row];
      float4 m  = ((const float4*)(mu   + (size_t)row * 256))[lane];
      float4 v  = ((const float4*)(var  + (size_t)row * 256))[lane];
      float4 mh = ((const float4*)(muh  + (size_t)f   * 256))[lane];
      float4 vh = ((const float4*)(varh + (size_t)f   * 256))[lane];
      float4 d, q, p;
      float s, sb, ds;
      s = sqrtf(v.x); sb = sqrtf(vh.x); ds = s - sb; d.x = m.x - mh.x; q.x = ds * ds; p.x = ds * sb;
      s = sqrtf(v.y); sb = sqrtf(vh.y); ds = s - sb; d.y = m.y - mh.y; q.y = ds * ds; p.y = ds * sb;
      s = sqrtf(v.z); sb = sqrtf(vh.z); ds = s - sb; d.z = m.z - mh.z; q.z = ds * ds; p.z = ds * sb;
      s = sqrtf(v.w); sb = sqrtf(vh.w); ds = s - sb; d.w = m.w - mh.w; q.w = ds * ds; p.w = ds * sb;
      uint4 au;
      au.x = bf16pair(d.x, d.y);
      au.y = bf16pair(d.z, d.w);
      au.z = bf16pair(q.x, q.y);
      au.w = bf16pair(q.z, q.w);
      ((uint4*)(A + (size_t)row * 256))[lane] = au;
      uint2 mu2;
      mu2.x = bf16pair(p.x, p.y);
      mu2.y = bf16pair(p.z, p.w);
      ((uint2*)(M + (size_t)row * 128))[lane] = mu2;
    }
    if (WITH_FB && row < n_full) {
      int f = ffield[row];
      float4 mb = ((const float4*)(muh  + (size_t)f * 256))[lane];
      float4 vb = ((const float4*)(varh + (size_t)f * 256))[lane];
      uint4 fu;
      fu.x = bf16pair(mb.x, mb.y);
      fu.y = bf16pair(mb.z, mb.w);
      fu.z = bf16pair(vb.x, vb.y);
      fu.w = bf16pair(vb.z, vb.w);
      ((uint4*)(FB + (size_t)row * 256))[lane] = fu;
    }
  }
}

// ===========================================================================
// k_scan3: blockIdx.x = matrix index; exclusive scan of per-row counts.
// ===========================================================================
__global__ __launch_bounds__(256) void k_scan3(const int* __restrict__ cnt_all,
                                               int* __restrict__ base_all,
                                               int* __restrict__ cur_all, int n) {
  const int* cnt = cnt_all + blockIdx.x * n;
  int* base = base_all + blockIdx.x * (n + 1);
  int* cur = cur_all + blockIdx.x * n;
  __shared__ int sums[256];
  int tid = threadIdx.x;
  int chunk = (n + 255) / 256;
  int s = tid * chunk, e = min(s + chunk, n);
  int local = 0;
  for (int i = s; i < e; ++i) local += cnt[i];
  sums[tid] = local;
  __syncthreads();
  for (int off = 1; off < 256; off <<= 1) {
    int v = (tid >= off) ? sums[tid - off] : 0;
    __syncthreads();
    sums[tid] += v;
    __syncthreads();
  }
  int run = (tid == 0) ? 0 : sums[tid - 1];
  for (int i = s; i < e; ++i) {
    base[i] = run;
    cur[i] = run;
    run += cnt[i];
  }
  if (tid == 255) base[n] = sums[255];
}

// ===========================================================================
// k_scatter3: edges -> CSR order as (col, val_bits). madj val pre-scaled 2x.
// RESOLVE_F (tier2 only): fadj col resolved through ffield here.
// ===========================================================================
template <bool RESOLVE_F>
__global__ __launch_bounds__(256) void k_scatter3(
    const int* __restrict__ ra, const int* __restrict__ ca, const float* __restrict__ va,
    const int* __restrict__ rf, const int* __restrict__ cf, const float* __restrict__ vf,
    const int* __restrict__ rm, const int* __restrict__ cm, const float* __restrict__ vm,
    const int* __restrict__ ffield,
    int* __restrict__ cur_all, uint2* __restrict__ ord, int nnz, int n_out) {
  int total = 3 * nnz;
  for (int i = blockIdx.x * blockDim.x + threadIdx.x; i < total;
       i += gridDim.x * blockDim.x) {
    int m = (i >= nnz) + (i >= 2 * nnz);
    int e = i - m * nnz;
    const int* rp = (m == 0) ? ra : (m == 1) ? rf : rm;
    const int* cp = (m == 0) ? ca : (m == 1) ? cf : cm;
    const float* vp = (m == 0) ? va : (m == 1) ? vf : vm;
    int r = rp[e];
    int c = cp[e];
    float w = vp[e];
    if (RESOLVE_F && m == 1) c = ffield[c];
    if (m == 2) w = 2.0f * w;
    int pos = atomicAdd(&cur_all[m * n_out + r], 1);
    ord[(size_t)m * nnz + pos] = make_uint2((u32)c, __float_as_uint(w));
  }
}

// ===========================================================================
// k_agg: one wave per output row; register accumulation over all three CSR
// edge lists; single write per output row, relu+eps fused.
// HAS_FB: fadj reads bf16 FB (1 KB/row) instead of f32 muh/varh (2 KB).
// ===========================================================================
template <bool HAS_FB>
__global__ __launch_bounds__(256) void k_agg(
    const float* __restrict__ mu, const float* __restrict__ var,
    const float* __restrict__ muh, const float* __restrict__ varh,
    const u32* __restrict__ A, const u32* __restrict__ M,
    const u32* __restrict__ FB,
    const int* __restrict__ base_all, const uint2* __restrict__ ord,
    float* __restrict__ out0, float* __restrict__ out1, int n_out, int nnz) {
  int r = (int)((blockIdx.x * blockDim.x + threadIdx.x) >> 6);
  int lane = threadIdx.x & 63;
  if (r >= n_out) return;

  float4 am = make_float4(0.f, 0.f, 0.f, 0.f);
  float4 av = make_float4(0.f, 0.f, 0.f, 0.f);

  // ---- adj: am += w*dmu[c]; av += w^2*ds2[c]  (bf16 interleaved in A) ----
  {
    const int* base = base_all;
    const uint2* o = ord;
    int b0 = base[r], b1 = base[r + 1];
    int p = b0;
    for (; p + 1 < b1; p += 2) {
      uint2 cv0 = o[p], cv1 = o[p + 1];
      float w0 = __uint_as_float(cv0.y), w1 = __uint_as_float(cv1.y);
      uint4 u0 = ((const uint4*)(A + (size_t)cv0.x * 256))[lane];
      uint4 u1 = ((const uint4*)(A + (size_t)cv1.x * 256))[lane];
      float q0 = w0 * w0, q1 = w1 * w1;
      am.x += w0 * bf_lo(u0.x) + w1 * bf_lo(u1.x);
      am.y += w0 * bf_hi(u0.x) + w1 * bf_hi(u1.x);
      am.z += w0 * bf_lo(u0.y) + w1 * bf_lo(u1.y);
      am.w += w0 * bf_hi(u0.y) + w1 * bf_hi(u1.y);
      av.x += q0 * bf_lo(u0.z) + q1 * bf_lo(u1.z);
      av.y += q0 * bf_hi(u0.z) + q1 * bf_hi(u1.z);
      av.z += q0 * bf_lo(u0.w) + q1 * bf_lo(u1.w);
      av.w += q0 * bf_hi(u0.w) + q1 * bf_hi(u1.w);
    }
    if (p < b1) {
      uint2 cv0 = o[p];
      float w0 = __uint_as_float(cv0.y);
      uint4 u0 = ((const uint4*)(A + (size_t)cv0.x * 256))[lane];
      float q0 = w0 * w0;
      am.x += w0 * bf_lo(u0.x); am.y += w0 * bf_hi(u0.x);
      am.z += w0 * bf_lo(u0.y); am.w += w0 * bf_hi(u0.y);
      av.x += q0 * bf_lo(u0.z); av.y += q0 * bf_hi(u0.z);
      av.z += q0 * bf_lo(u0.w); av.w += q0 * bf_hi(u0.w);
    }
  }

  // ---- fadj: am += w*mu_bar; av += w^2*var_bar ----
  {
    const int* base = base_all + (n_out + 1);
    const uint2* o = ord + (size_t)nnz;
    int b0 = base[r], b1 = base[r + 1];
    int p = b0;
    if (HAS_FB) {
      for (; p + 1 < b1; p += 2) {
        uint2 cv0 = o[p], cv1 = o[p + 1];
        float w0 = __uint_as_float(cv0.y), w1 = __uint_as_float(cv1.y);
        uint4 u0 = ((const uint4*)(FB + (size_t)cv0.x * 256))[lane];
        uint4 u1 = ((const uint4*)(FB + (size_t)cv1.x * 256))[lane];
        float q0 = w0 * w0, q1 = w1 * w1;
        am.x += w0 * bf_lo(u0.x) + w1 * bf_lo(u1.x);
        am.y += w0 * bf_hi(u0.x) + w1 * bf_hi(u1.x);
        am.z += w0 * bf_lo(u0.y) + w1 * bf_lo(u1.y);
        am.w += w0 * bf_hi(u0.y) + w1 * bf_hi(u1.y);
        av.x += q0 * bf_lo(u0.z) + q1 * bf_lo(u1.z);
        av.y += q0 * bf_hi(u0.z) + q1 * bf_hi(u1.z);
        av.z += q0 * bf_lo(u0.w) + q1 * bf_lo(u1.w);
        av.w += q0 * bf_hi(u0.w) + q1 * bf_hi(u1.w);
      }
      if (p < b1) {
        uint2 cv0 = o[p];
        float w0 = __uint_as_float(cv0.y);
        uint4 u0 = ((const uint4*)(FB + (size_t)cv0.x * 256))[lane];
        float q0 = w0 * w0;
        am.x += w0 * bf_lo(u0.x); am.y += w0 * bf_hi(u0.x);
        am.z += w0 * bf_lo(u0.y); am.w += w0 * bf_hi(u0.y);
        av.x += q0 * bf_lo(u0.z); av.y += q0 * bf_hi(u0.z);
        av.z += q0 * bf_lo(u0.w); av.w += q0 * bf_hi(u0.w);
      }
    } else {
      for (; p + 1 < b1; p += 2) {
        uint2 cv0 = o[p], cv1 = o[p + 1];
        float w0 = __uint_as_float(cv0.y), w1 = __uint_as_float(cv1.y);
        float4 m0 = ((const float4*)(muh  + (size_t)cv0.x * 256))[lane];
        float4 v0 = ((const float4*)(varh + (size_t)cv0.x * 256))[lane];
        float4 m1 = ((const float4*)(muh  + (size_t)cv1.x * 256))[lane];
        float4 v1 = ((const float4*)(varh + (size_t)cv1.x * 256))[lane];
        float q0 = w0 * w0, q1 = w1 * w1;
        am.x += w0 * m0.x + w1 * m1.x; am.y += w0 * m0.y + w1 * m1.y;
        am.z += w0 * m0.z + w1 * m1.z; am.w += w0 * m0.w + w1 * m1.w;
        av.x += q0 * v0.x + q1 * v1.x; av.y += q0 * v0.y + q1 * v1.y;
        av.z += q0 * v0.z + q1 * v1.z; av.w += q0 * v0.w + q1 * v1.w;
      }
      if (p < b1) {
        uint2 cv0 = o[p];
        float w0 = __uint_as_float(cv0.y);
        float4 m0 = ((const float4*)(muh  + (size_t)cv0.x * 256))[lane];
        float4 v0 = ((const float4*)(varh + (size_t)cv0.x * 256))[lane];
        float q0 = w0 * w0;
        am.x += w0 * m0.x; am.y += w0 * m0.y; am.z += w0 * m0.z; am.w += w0 * m0.w;
        av.x += q0 * v0.x; av.y += q0 * v0.y; av.z += q0 * v0.z; av.w += q0 * v0.w;
      }
    }
  }

  // ---- madj: av += (2w)*ms[c]  (scale folded at scatter; bf16 in M) ----
  {
    const int* base = base_all + 2 * (n_out + 1);
    const uint2* o = ord + 2 * (size_t)nnz;
    int b0 = base[r], b1 = base[r + 1];
    int p = b0;
    for (; p + 1 < b1; p += 2) {
      uint2 cv0 = o[p], cv1 = o[p + 1];
      float w0 = __uint_as_float(cv0.y), w1 = __uint_as_float(cv1.y);
      uint2 x0 = ((const uint2*)(M + (size_t)cv0.x * 128))[lane];
      uint2 x1 = ((const uint2*)(M + (size_t)cv1.x * 128))[lane];
      av.x += w0 * bf_lo(x0.x) + w1 * bf_lo(x1.x);
      av.y += w0 * bf_hi(x0.x) + w1 * bf_hi(x1.x);
      av.z += w0 * bf_lo(x0.y) + w1 * bf_lo(x1.y);
      av.w += w0 * bf_hi(x0.y) + w1 * bf_hi(x1.y);
    }
    if (p < b1) {
      uint2 cv0 = o[p];
      float w0 = __uint_as_float(cv0.y);
      uint2 x0 = ((const uint2*)(M + (size_t)cv0.x * 128))[lane];
      av.x += w0 * bf_lo(x0.x); av.y += w0 * bf_hi(x0.x);
      av.z += w0 * bf_lo(x0.y); av.w += w0 * bf_hi(x0.y);
    }
  }

  // ---- epilogue ----
  av.x = fmaxf(av.x, 0.f) + EPS_F;
  av.y = fmaxf(av.y, 0.f) + EPS_F;
  av.z = fmaxf(av.z, 0.f) + EPS_F;
  av.w = fmaxf(av.w, 0.f) + EPS_F;
  float4 msf = ((const float4*)(mu  + (size_t)r * 256))[lane];
  float4 vsf = ((const float4*)(var + (size_t)r * 256))[lane];
  ((float4*)(out0 + (size_t)r * 512))[lane]       = msf;
  ((float4*)(out0 + (size_t)r * 512 + 256))[lane] = am;
  ((float4*)(out1 + (size_t)r * 512))[lane]       = vsf;
  ((float4*)(out1 + (size_t)r * 512 + 256))[lane] = av;
}

// ===========================================================================
// Fallback (tiny workspace): atomic scatter path, recompute variant.
// ===========================================================================
__global__ __launch_bounds__(256) void k_init_out(
    const float* __restrict__ mu, const float* __restrict__ var,
    float* __restrict__ out0, float* __restrict__ out1) {
  int r = blockIdx.x;
  int t = threadIdx.x;
  const float4 z = make_float4(0.f, 0.f, 0.f, 0.f);
  if (t < 128) {
    float4* dst = (float4*)(out0 + (size_t)r * 512);
    dst[t] = (t < 64) ? ((const float4*)(mu + (size_t)r * 256))[t] : z;
  } else {
    int u = t - 128;
    float4* dst = (float4*)(out1 + (size_t)r * 512);
    dst[u] = (u < 64) ? ((const float4*)(var + (size_t)r * 256))[u] : z;
  }
}

__global__ __launch_bounds__(256) void k_edge_adj_fb(
    const float* __restrict__ vals, const int* __restrict__ rows,
    const int* __restrict__ cols,
    const float* __restrict__ mu, const float* __restrict__ var,
    const float* __restrict__ muh, const float* __restrict__ varh,
    const int* __restrict__ ifield,
    float* __restrict__ out0, float* __restrict__ out1, int nnz) {
  int wave = (int)((blockIdx.x * blockDim.x + threadIdx.x) >> 6);
  int lane = threadIdx.x & 63;
  int nw = (int)((gridDim.x * blockDim.x) >> 6);
  for (int e = wave; e < nnz; e += nw) {
    float w = vals[e];
    int r = rows[e];
    int c = cols[e];
    int f = ifield[c];
    float4 m  = ((const float4*)(mu   + (size_t)c * 256))[lane];
    float4 v  = ((const float4*)(var  + (size_t)c * 256))[lane];
    float4 mh = ((const float4*)(muh  + (size_t)f * 256))[lane];
    float4 vh = ((const float4*)(varh + (size_t)f * 256))[lane];
    float4 xm, xv;
    float ds;
    xm.x = m.x - mh.x; ds = sqrtf(v.x) - sqrtf(vh.x); xv.x = ds * ds;
    xm.y = m.y - mh.y; ds = sqrtf(v.y) - sqrtf(vh.y); xv.y = ds * ds;
    xm.z = m.z - mh.z; ds = sqrtf(v.z) - sqrtf(vh.z); xv.z = ds * ds;
    xm.w = m.w - mh.w; ds = sqrtf(v.w) - sqrtf(vh.w); xv.w = ds * ds;
    float w2 = w * w;
    float* om = out0 + (size_t)r * 512 + 256 + lane * 4;
    float* ov = out1 + (size_t)r * 512 + 256 + lane * 4;
    atomicAdd(om + 0, w * xm.x); atomicAdd(om + 1, w * xm.y);
    atomicAdd(om + 2, w * xm.z); atomicAdd(om + 3, w * xm.w);
    atomicAdd(ov + 0, w2 * xv.x); atomicAdd(ov + 1, w2 * xv.y);
    atomicAdd(ov + 2, w2 * xv.z); atomicAdd(ov + 3, w2 * xv.w);
  }
}

__global__ __launch_bounds__(256) void k_edge_fadj_fb(
    const float* __restrict__ vals, const int* __restrict__ rows,
    const int* __restrict__ cols,
    const float* __restrict__ muh, const float* __restrict__ varh,
    const int* __restrict__ ffield,
    float* __restrict__ out0, float* __restrict__ out1, int nnz) {
  int wave = (int)((blockIdx.x * blockDim.x + threadIdx.x) >> 6);
  int lane = threadIdx.x & 63;
  int nw = (int)((gridDim.x * blockDim.x) >> 6);
  for (int e = wave; e < nnz; e += nw) {
    float w = vals[e];
    int r = rows[e];
    int f = ffield[cols[e]];
    float4 mb = ((const float4*)(muh  + (size_t)f * 256))[lane];
    float4 vb = ((const float4*)(varh + (size_t)f * 256))[lane];
    float w2 = w * w;
    float* om = out0 + (size_t)r * 512 + 256 + lane * 4;
    float* ov = out1 + (size_t)r * 512 + 256 + lane * 4;
    atomicAdd(om + 0, w * mb.x); atomicAdd(om + 1, w * mb.y);
    atomicAdd(om + 2, w * mb.z); atomicAdd(om + 3, w * mb.w);
    atomicAdd(ov + 0, w2 * vb.x); atomicAdd(ov + 1, w2 * vb.y);
    atomicAdd(ov + 2, w2 * vb.z); atomicAdd(ov + 3, w2 * vb.w);
  }
}

__global__ __launch_bounds__(256) void k_edge_madj_fb(
    const float* __restrict__ vals, const int* __restrict__ rows,
    const int* __restrict__ cols,
    const float* __restrict__ var, const float* __restrict__ varh,
    const int* __restrict__ ifield,
    float* __restrict__ out1, int nnz) {
  int wave = (int)((blockIdx.x * blockDim.x + threadIdx.x) >> 6);
  int lane = threadIdx.x & 63;
  int nw = (int)((gridDim.x * blockDim.x) >> 6);
  for (int e = wave; e < nnz; e += nw) {
    float w = 2.0f * vals[e];
    int r = rows[e];
    int c = cols[e];
    int f = ifield[c];
    float4 v  = ((const float4*)(var  + (size_t)c * 256))[lane];
    float4 vh = ((const float4*)(varh + (size_t)f * 256))[lane];
    float4 x;
    float sb;
    sb = sqrtf(vh.x); x.x = (sqrtf(v.x) - sb) * sb;
    sb = sqrtf(vh.y); x.y = (sqrtf(v.y) - sb) * sb;
    sb = sqrtf(vh.z); x.z = (sqrtf(v.z) - sb) * sb;
    sb = sqrtf(vh.w); x.w = (sqrtf(v.w) - sb) * sb;
    float* ov = out1 + (size_t)r * 512 + 256 + lane * 4;
    atomicAdd(ov + 0, w * x.x); atomicAdd(ov + 1, w * x.y);
    atomicAdd(ov + 2, w * x.z); atomicAdd(ov + 3, w * x.w);
  }
}

__global__ __launch_bounds__(256) void k_final(float* __restrict__ out1, int n_out) {
  int total = n_out * 64;
  for (int i = blockIdx.x * blockDim.x + threadIdx.x; i < total;
       i += gridDim.x * blockDim.x) {
    int r = i >> 6;
    int q = i & 63;
    float4* p = (float4*)(out1 + (size_t)r * 512 + 256) + q;
    float4 v = *p;
    v.x = fmaxf(v.x, 0.f) + EPS_F;
    v.y = fmaxf(v.y, 0.f) + EPS_F;
    v.z = fmaxf(v.z, 0.f) + EPS_F;
    v.w = fmaxf(v.w, 0.f) + EPS_F;
    *p = v;
  }
}

// ===========================================================================
extern "C" void kernel_launch(void* const* d_in, const int* in_sizes, int n_in_args,
                              void* d_out, int out_size, void* d_ws, size_t ws_size,
                              hipStream_t stream) {
  const float* mu        = (const float*)d_in[0];
  const float* var       = (const float*)d_in[1];
  const float* muh       = (const float*)d_in[2];
  const float* varh      = (const float*)d_in[3];
  const float* adj_vals  = (const float*)d_in[4];
  const float* fadj_vals = (const float*)d_in[5];
  const float* madj_vals = (const float*)d_in[6];
  const int* adj_rows    = (const int*)d_in[7];
  const int* adj_cols    = (const int*)d_in[8];
  const int* fadj_rows   = (const int*)d_in[9];
  const int* fadj_cols   = (const int*)d_in[10];
  const int* madj_rows   = (const int*)d_in[11];
  const int* madj_cols   = (const int*)d_in[12];
  const int* ifield      = (const int*)d_in[13];
  const int* ffield      = (const int*)d_in[14];

  const int n_out  = out_size / 1024;    // two outputs, 512 cols each
  const int n_in   = in_sizes[0] / 256;
  const int nnz    = in_sizes[4];
  const int n_full = in_sizes[14];       // ffield length

  float* out0 = (float*)d_out;
  float* out1 = out0 + (size_t)n_out * 512;

  // Workspace layout (u32 units): A, M, [FB], ord(uint2), cnt, base, cur
  const size_t uA = (size_t)n_in * 256;
  const size_t uM = (size_t)n_in * 128;
  const size_t uFB = (size_t)n_full * 256;
  const size_t uOrd = (size_t)3 * nnz * 2;
  const size_t uCnt = (size_t)3 * n_out;
  const size_t uBase = (size_t)3 * (n_out + 1);
  const size_t need2 = (uA + uM + uOrd + uCnt + uBase + uCnt) * sizeof(u32);
  const size_t need1 = need2 + uFB * sizeof(u32);

  if (ws_size >= need2) {
    const bool fb = (ws_size >= need1);
    u32* A = (u32*)d_ws;
    u32* M = A + uA;
    u32* FB = M + uM;                       // only valid if fb
    u32* tail = fb ? (FB + uFB) : (M + uM);
    uint2* ord = (uint2*)tail;
    int* cnt  = (int*)(tail + uOrd);
    int* base = cnt + uCnt;
    int* cur  = base + uBase;

    hipMemsetAsync(cnt, 0, uCnt * sizeof(int), stream);
    if (fb) {
      k_pre<true><<<4096, 256, 0, stream>>>(mu, var, muh, varh, ifield, ffield,
                                            adj_rows, fadj_rows, madj_rows, cnt,
                                            A, M, FB, n_in, n_full, n_out, nnz);
    } else {
      k_pre<false><<<4096, 256, 0, stream>>>(mu, var, muh, varh, ifield, ffield,
                                             adj_rows, fadj_rows, madj_rows, cnt,
                                             A, M, nullptr, n_in, n_full, n_out, nnz);
    }
    k_scan3<<<3, 256, 0, stream>>>(cnt, base, cur, n_out);
    if (fb) {
      k_scatter3<false><<<1024, 256, 0, stream>>>(adj_rows, adj_cols, adj_vals,
                                                  fadj_rows, fadj_cols, fadj_vals,
                                                  madj_rows, madj_cols, madj_vals,
                                                  ffield, cur, ord, nnz, n_out);
    } else {
      k_scatter3<true><<<1024, 256, 0, stream>>>(adj_rows, adj_cols, adj_vals,
                                                 fadj_rows, fadj_cols, fadj_vals,
                                                 madj_rows, madj_cols, madj_vals,
                                                 ffield, cur, ord, nnz, n_out);
    }
    int blocks = (n_out * 64 + 255) / 256;
    if (fb) {
      k_agg<true><<<blocks, 256, 0, stream>>>(mu, var, muh, varh, A, M, FB, base, ord,
                                              out0, out1, n_out, nnz);
    } else {
      k_agg<false><<<blocks, 256, 0, stream>>>(mu, var, muh, varh, A, M, nullptr, base, ord,
                                               out0, out1, n_out, nnz);
    }
  } else {
    k_init_out<<<n_out, 256, 0, stream>>>(mu, var, out0, out1);
    k_edge_adj_fb<<<4096, 256, 0, stream>>>(adj_vals, adj_rows, adj_cols,
                                            mu, var, muh, varh, ifield, out0, out1, nnz);
    k_edge_madj_fb<<<4096, 256, 0, stream>>>(madj_vals, madj_rows, madj_cols,
                                             var, varh, ifield, out1, nnz);
    k_edge_fadj_fb<<<4096, 256, 0, stream>>>(fadj_vals, fadj_rows, fadj_cols,
                                             muh, varh, ffield, out0, out1, nnz);
    k_final<<<4096, 256, 0, stream>>>(out1, n_out);
  }
}

// Round 6
// 310.685 us; speedup vs baseline: 14.3039x; 1.0105x over previous
//
#include <hip/hip_runtime.h>

#define EPS_F 1e-10f

typedef unsigned int u32;

// bf16 pack (RTN) / unpack helpers -------------------------------------------
__device__ __forceinline__ u32 bf16pair(float lo, float hi) {
  u32 a = __float_as_uint(lo);
  u32 b = __float_as_uint(hi);
  a = a + 0x7FFFu + ((a >> 16) & 1u);
  b = b + 0x7FFFu + ((b >> 16) & 1u);
  return (a >> 16) | (b & 0xFFFF0000u);
}
__device__ __forceinline__ float bf_lo(u32 u) { return __uint_as_float(u << 16); }
__device__ __forceinline__ float bf_hi(u32 u) { return __uint_as_float(u & 0xFFFF0000u); }

// accumulate helpers (inline functions — no macro token-capture hazards)
__device__ __forceinline__ void acc_am(float4& am, uint4 u, float W) {
  am.x += W * bf_lo(u.x); am.y += W * bf_hi(u.x);
  am.z += W * bf_lo(u.y); am.w += W * bf_hi(u.y);
}
__device__ __forceinline__ void acc_av(float4& av, uint4 u, float Q) {
  av.x += Q * bf_lo(u.z); av.y += Q * bf_hi(u.z);
  av.z += Q * bf_lo(u.w); av.w += Q * bf_hi(u.w);
}
__device__ __forceinline__ void acc_m(float4& av, uint2 x, float W) {
  av.x += W * bf_lo(x.x); av.y += W * bf_hi(x.x);
  av.z += W * bf_lo(x.y); av.w += W * bf_hi(x.y);
}

// ===========================================================================
// k_count: per-row edge counts for all 3 matrices.
// ===========================================================================
__global__ __launch_bounds__(256) void k_count(
    const int* __restrict__ ra, const int* __restrict__ rf,
    const int* __restrict__ rm, int* __restrict__ cnt, int nnz, int n_out) {
  int total = 3 * nnz;
  for (int i = blockIdx.x * blockDim.x + threadIdx.x; i < total;
       i += gridDim.x * blockDim.x) {
    int m = (i >= nnz) + (i >= 2 * nnz);
    int e = i - m * nnz;
    const int* rp = (m == 0) ? ra : (m == 1) ? rf : rm;
    atomicAdd(&cnt[m * n_out + rp[e]], 1);
  }
}

// ===========================================================================
// k_scan3: blockIdx.x = matrix index; exclusive scan of per-row counts.
// ===========================================================================
__global__ __launch_bounds__(256) void k_scan3(const int* __restrict__ cnt_all,
                                               int* __restrict__ base_all,
                                               int* __restrict__ cur_all, int n) {
  const int* cnt = cnt_all + blockIdx.x * n;
  int* base = base_all + blockIdx.x * (n + 1);
  int* cur = cur_all + blockIdx.x * n;
  __shared__ int sums[256];
  int tid = threadIdx.x;
  int chunk = (n + 255) / 256;
  int s = tid * chunk, e = min(s + chunk, n);
  int local = 0;
  for (int i = s; i < e; ++i) local += cnt[i];
  sums[tid] = local;
  __syncthreads();
  for (int off = 1; off < 256; off <<= 1) {
    int v = (tid >= off) ? sums[tid - off] : 0;
    __syncthreads();
    sums[tid] += v;
    __syncthreads();
  }
  int run = (tid == 0) ? 0 : sums[tid - 1];
  for (int i = s; i < e; ++i) {
    base[i] = run;
    cur[i] = run;
    run += cnt[i];
  }
  if (tid == 255) base[n] = sums[255];
}

// ===========================================================================
// k_pre_scatter: fused (a) CSR scatter for all 3 matrices, (b) per-input-row
// intermediates A/M (bf16), (c) [tier1] pre-gathered fadj source FB (bf16).
// Rows phase uses CONTIGUOUS per-wave chunks so streaming reads/writes hit
// one DRAM page per wave.
// A[row]  : 256 u32 = per lane [dmu x4 | ds2 x4]           (1 KB/row)
// M[row]  : 128 u32 = per lane [ms x4]                     (512 B/row)
// FB[col] : 256 u32 = per lane [mu_bar x4 | var_bar x4]    (1 KB/row)
// ===========================================================================
template <bool WITH_FB>
__global__ __launch_bounds__(256) void k_pre_scatter(
    const float* __restrict__ mu, const float* __restrict__ var,
    const float* __restrict__ muh, const float* __restrict__ varh,
    const int* __restrict__ ifield, const int* __restrict__ ffield,
    const int* __restrict__ ra, const int* __restrict__ ca, const float* __restrict__ va,
    const int* __restrict__ rf, const int* __restrict__ cf, const float* __restrict__ vf,
    const int* __restrict__ rm, const int* __restrict__ cm, const float* __restrict__ vm,
    int* __restrict__ cur_all, uint2* __restrict__ ord,
    u32* __restrict__ A, u32* __restrict__ M, u32* __restrict__ FB,
    int n_in, int n_full, int n_out, int nnz) {
  int tid = blockIdx.x * blockDim.x + threadIdx.x;
  int nth = gridDim.x * blockDim.x;

  // --- (a) CSR scatter, grid-strided over 3*nnz ---
  int total = 3 * nnz;
  for (int i = tid; i < total; i += nth) {
    int m = (i >= nnz) + (i >= 2 * nnz);
    int e = i - m * nnz;
    const int* rp = (m == 0) ? ra : (m == 1) ? rf : rm;
    const int* cp = (m == 0) ? ca : (m == 1) ? cf : cm;
    const float* vp = (m == 0) ? va : (m == 1) ? vf : vm;
    int r = rp[e];
    int c = cp[e];
    float w = vp[e];
    if (!WITH_FB && m == 1) c = ffield[c];  // no FB: resolve field here
    if (m == 2) w = 2.0f * w;
    int pos = atomicAdd(&cur_all[m * n_out + r], 1);
    ord[(size_t)m * nnz + pos] = make_uint2((u32)c, __float_as_uint(w));
  }

  // --- (b)+(c) contiguous row chunks per wave ---
  int wave = tid >> 6;
  int lane = tid & 63;
  int nw = nth >> 6;
  int nr = WITH_FB ? (n_in > n_full ? n_in : n_full) : n_in;
  int rpw = (nr + nw - 1) / nw;
  int r0 = wave * rpw;
  int r1 = min(nr, r0 + rpw);
  for (int row = r0; row < r1; ++row) {
    if (row < n_in) {
      int f = ifield[row];
      float4 m  = ((const float4*)(mu   + (size_t)row * 256))[lane];
      float4 v  = ((const float4*)(var  + (size_t)row * 256))[lane];
      float4 mh = ((const float4*)(muh  + (size_t)f   * 256))[lane];
      float4 vh = ((const float4*)(varh + (size_t)f   * 256))[lane];
      float4 d, q, p;
      float s, sb, ds;
      s = sqrtf(v.x); sb = sqrtf(vh.x); ds = s - sb; d.x = m.x - mh.x; q.x = ds * ds; p.x = ds * sb;
      s = sqrtf(v.y); sb = sqrtf(vh.y); ds = s - sb; d.y = m.y - mh.y; q.y = ds * ds; p.y = ds * sb;
      s = sqrtf(v.z); sb = sqrtf(vh.z); ds = s - sb; d.z = m.z - mh.z; q.z = ds * ds; p.z = ds * sb;
      s = sqrtf(v.w); sb = sqrtf(vh.w); ds = s - sb; d.w = m.w - mh.w; q.w = ds * ds; p.w = ds * sb;
      uint4 au;
      au.x = bf16pair(d.x, d.y);
      au.y = bf16pair(d.z, d.w);
      au.z = bf16pair(q.x, q.y);
      au.w = bf16pair(q.z, q.w);
      ((uint4*)(A + (size_t)row * 256))[lane] = au;
      uint2 mu2;
      mu2.x = bf16pair(p.x, p.y);
      mu2.y = bf16pair(p.z, p.w);
      ((uint2*)(M + (size_t)row * 128))[lane] = mu2;
    }
    if (WITH_FB && row < n_full) {
      int f = ffield[row];
      float4 mb = ((const float4*)(muh  + (size_t)f * 256))[lane];
      float4 vb = ((const float4*)(varh + (size_t)f * 256))[lane];
      uint4 fu;
      fu.x = bf16pair(mb.x, mb.y);
      fu.y = bf16pair(mb.z, mb.w);
      fu.z = bf16pair(vb.x, vb.y);
      fu.w = bf16pair(vb.z, vb.w);
      ((uint4*)(FB + (size_t)row * 256))[lane] = fu;
    }
  }
}

// ===========================================================================
// k_agg: one wave per output row; register accumulation over all three CSR
// edge lists (4-edge unroll => 4 independent 1 KB gathers in flight).
// Single write per output row, relu+eps fused.
// ===========================================================================
template <bool HAS_FB>
__global__ __launch_bounds__(256) void k_agg(
    const float* __restrict__ mu, const float* __restrict__ var,
    const float* __restrict__ muh, const float* __restrict__ varh,
    const u32* __restrict__ A, const u32* __restrict__ M,
    const u32* __restrict__ FB,
    const int* __restrict__ base_all, const uint2* __restrict__ ord,
    float* __restrict__ out0, float* __restrict__ out1, int n_out, int nnz) {
  int r = (int)((blockIdx.x * blockDim.x + threadIdx.x) >> 6);
  int lane = threadIdx.x & 63;
  if (r >= n_out) return;

  // self-copy loads issued early; consumed in the epilogue.
  float4 msf = ((const float4*)(mu  + (size_t)r * 256))[lane];
  float4 vsf = ((const float4*)(var + (size_t)r * 256))[lane];

  float4 am = make_float4(0.f, 0.f, 0.f, 0.f);
  float4 av = make_float4(0.f, 0.f, 0.f, 0.f);

  // ---- adj: am += w*dmu[c]; av += w^2*ds2[c]  (bf16 interleaved in A) ----
  {
    const int* base = base_all;
    const uint2* o = ord;
    int b0 = base[r], b1 = base[r + 1];
    int p = b0;
    for (; p + 3 < b1; p += 4) {
      uint2 cv0 = o[p], cv1 = o[p + 1], cv2 = o[p + 2], cv3 = o[p + 3];
      uint4 u0 = ((const uint4*)(A + (size_t)cv0.x * 256))[lane];
      uint4 u1 = ((const uint4*)(A + (size_t)cv1.x * 256))[lane];
      uint4 u2 = ((const uint4*)(A + (size_t)cv2.x * 256))[lane];
      uint4 u3 = ((const uint4*)(A + (size_t)cv3.x * 256))[lane];
      float w0 = __uint_as_float(cv0.y), w1 = __uint_as_float(cv1.y);
      float w2 = __uint_as_float(cv2.y), w3 = __uint_as_float(cv3.y);
      acc_am(am, u0, w0); acc_am(am, u1, w1); acc_am(am, u2, w2); acc_am(am, u3, w3);
      acc_av(av, u0, w0 * w0); acc_av(av, u1, w1 * w1);
      acc_av(av, u2, w2 * w2); acc_av(av, u3, w3 * w3);
    }
    for (; p < b1; ++p) {
      uint2 cv0 = o[p];
      float w0 = __uint_as_float(cv0.y);
      uint4 u0 = ((const uint4*)(A + (size_t)cv0.x * 256))[lane];
      acc_am(am, u0, w0); acc_av(av, u0, w0 * w0);
    }
  }

  // ---- fadj: am += w*mu_bar; av += w^2*var_bar ----
  {
    const int* base = base_all + (n_out + 1);
    const uint2* o = ord + (size_t)nnz;
    int b0 = base[r], b1 = base[r + 1];
    int p = b0;
    if (HAS_FB) {
      for (; p + 3 < b1; p += 4) {
        uint2 cv0 = o[p], cv1 = o[p + 1], cv2 = o[p + 2], cv3 = o[p + 3];
        uint4 u0 = ((const uint4*)(FB + (size_t)cv0.x * 256))[lane];
        uint4 u1 = ((const uint4*)(FB + (size_t)cv1.x * 256))[lane];
        uint4 u2 = ((const uint4*)(FB + (size_t)cv2.x * 256))[lane];
        uint4 u3 = ((const uint4*)(FB + (size_t)cv3.x * 256))[lane];
        float w0 = __uint_as_float(cv0.y), w1 = __uint_as_float(cv1.y);
        float w2 = __uint_as_float(cv2.y), w3 = __uint_as_float(cv3.y);
        acc_am(am, u0, w0); acc_am(am, u1, w1); acc_am(am, u2, w2); acc_am(am, u3, w3);
        acc_av(av, u0, w0 * w0); acc_av(av, u1, w1 * w1);
        acc_av(av, u2, w2 * w2); acc_av(av, u3, w3 * w3);
      }
      for (; p < b1; ++p) {
        uint2 cv0 = o[p];
        float w0 = __uint_as_float(cv0.y);
        uint4 u0 = ((const uint4*)(FB + (size_t)cv0.x * 256))[lane];
        acc_am(am, u0, w0); acc_av(av, u0, w0 * w0);
      }
    } else {
      for (; p + 1 < b1; p += 2) {
        uint2 cv0 = o[p], cv1 = o[p + 1];
        float w0 = __uint_as_float(cv0.y), w1 = __uint_as_float(cv1.y);
        float4 m0 = ((const float4*)(muh  + (size_t)cv0.x * 256))[lane];
        float4 v0 = ((const float4*)(varh + (size_t)cv0.x * 256))[lane];
        float4 m1 = ((const float4*)(muh  + (size_t)cv1.x * 256))[lane];
        float4 v1 = ((const float4*)(varh + (size_t)cv1.x * 256))[lane];
        float q0 = w0 * w0, q1 = w1 * w1;
        am.x += w0 * m0.x + w1 * m1.x; am.y += w0 * m0.y + w1 * m1.y;
        am.z += w0 * m0.z + w1 * m1.z; am.w += w0 * m0.w + w1 * m1.w;
        av.x += q0 * v0.x + q1 * v1.x; av.y += q0 * v0.y + q1 * v1.y;
        av.z += q0 * v0.z + q1 * v1.z; av.w += q0 * v0.w + q1 * v1.w;
      }
      if (p < b1) {
        uint2 cv0 = o[p];
        float w0 = __uint_as_float(cv0.y);
        float4 m0 = ((const float4*)(muh  + (size_t)cv0.x * 256))[lane];
        float4 v0 = ((const float4*)(varh + (size_t)cv0.x * 256))[lane];
        float q0 = w0 * w0;
        am.x += w0 * m0.x; am.y += w0 * m0.y; am.z += w0 * m0.z; am.w += w0 * m0.w;
        av.x += q0 * v0.x; av.y += q0 * v0.y; av.z += q0 * v0.z; av.w += q0 * v0.w;
      }
    }
  }

  // ---- madj: av += (2w)*ms[c]  (scale folded at scatter; bf16 in M) ----
  {
    const int* base = base_all + 2 * (n_out + 1);
    const uint2* o = ord + 2 * (size_t)nnz;
    int b0 = base[r], b1 = base[r + 1];
    int p = b0;
    for (; p + 3 < b1; p += 4) {
      uint2 cv0 = o[p], cv1 = o[p + 1], cv2 = o[p + 2], cv3 = o[p + 3];
      uint2 x0 = ((const uint2*)(M + (size_t)cv0.x * 128))[lane];
      uint2 x1 = ((const uint2*)(M + (size_t)cv1.x * 128))[lane];
      uint2 x2 = ((const uint2*)(M + (size_t)cv2.x * 128))[lane];
      uint2 x3 = ((const uint2*)(M + (size_t)cv3.x * 128))[lane];
      float w0 = __uint_as_float(cv0.y), w1 = __uint_as_float(cv1.y);
      float w2 = __uint_as_float(cv2.y), w3 = __uint_as_float(cv3.y);
      acc_m(av, x0, w0); acc_m(av, x1, w1); acc_m(av, x2, w2); acc_m(av, x3, w3);
    }
    for (; p < b1; ++p) {
      uint2 cv0 = o[p];
      float w0 = __uint_as_float(cv0.y);
      uint2 x0 = ((const uint2*)(M + (size_t)cv0.x * 128))[lane];
      acc_m(av, x0, w0);
    }
  }

  // ---- epilogue ----
  av.x = fmaxf(av.x, 0.f) + EPS_F;
  av.y = fmaxf(av.y, 0.f) + EPS_F;
  av.z = fmaxf(av.z, 0.f) + EPS_F;
  av.w = fmaxf(av.w, 0.f) + EPS_F;
  ((float4*)(out0 + (size_t)r * 512))[lane]       = msf;
  ((float4*)(out0 + (size_t)r * 512 + 256))[lane] = am;
  ((float4*)(out1 + (size_t)r * 512))[lane]       = vsf;
  ((float4*)(out1 + (size_t)r * 512 + 256))[lane] = av;
}

// ===========================================================================
// Fallback (tiny workspace): atomic scatter path, recompute variant.
// ===========================================================================
__global__ __launch_bounds__(256) void k_init_out(
    const float* __restrict__ mu, const float* __restrict__ var,
    float* __restrict__ out0, float* __restrict__ out1) {
  int r = blockIdx.x;
  int t = threadIdx.x;
  const float4 z = make_float4(0.f, 0.f, 0.f, 0.f);
  if (t < 128) {
    float4* dst = (float4*)(out0 + (size_t)r * 512);
    dst[t] = (t < 64) ? ((const float4*)(mu + (size_t)r * 256))[t] : z;
  } else {
    int u = t - 128;
    float4* dst = (float4*)(out1 + (size_t)r * 512);
    dst[u] = (u < 64) ? ((const float4*)(var + (size_t)r * 256))[u] : z;
  }
}

__global__ __launch_bounds__(256) void k_edge_adj_fb(
    const float* __restrict__ vals, const int* __restrict__ rows,
    const int* __restrict__ cols,
    const float* __restrict__ mu, const float* __restrict__ var,
    const float* __restrict__ muh, const float* __restrict__ varh,
    const int* __restrict__ ifield,
    float* __restrict__ out0, float* __restrict__ out1, int nnz) {
  int wave = (int)((blockIdx.x * blockDim.x + threadIdx.x) >> 6);
  int lane = threadIdx.x & 63;
  int nw = (int)((gridDim.x * blockDim.x) >> 6);
  for (int e = wave; e < nnz; e += nw) {
    float w = vals[e];
    int r = rows[e];
    int c = cols[e];
    int f = ifield[c];
    float4 m  = ((const float4*)(mu   + (size_t)c * 256))[lane];
    float4 v  = ((const float4*)(var  + (size_t)c * 256))[lane];
    float4 mh = ((const float4*)(muh  + (size_t)f * 256))[lane];
    float4 vh = ((const float4*)(varh + (size_t)f * 256))[lane];
    float4 xm, xv;
    float ds;
    xm.x = m.x - mh.x; ds = sqrtf(v.x) - sqrtf(vh.x); xv.x = ds * ds;
    xm.y = m.y - mh.y; ds = sqrtf(v.y) - sqrtf(vh.y); xv.y = ds * ds;
    xm.z = m.z - mh.z; ds = sqrtf(v.z) - sqrtf(vh.z); xv.z = ds * ds;
    xm.w = m.w - mh.w; ds = sqrtf(v.w) - sqrtf(vh.w); xv.w = ds * ds;
    float w2 = w * w;
    float* om = out0 + (size_t)r * 512 + 256 + lane * 4;
    float* ov = out1 + (size_t)r * 512 + 256 + lane * 4;
    atomicAdd(om + 0, w * xm.x); atomicAdd(om + 1, w * xm.y);
    atomicAdd(om + 2, w * xm.z); atomicAdd(om + 3, w * xm.w);
    atomicAdd(ov + 0, w2 * xv.x); atomicAdd(ov + 1, w2 * xv.y);
    atomicAdd(ov + 2, w2 * xv.z); atomicAdd(ov + 3, w2 * xv.w);
  }
}

__global__ __launch_bounds__(256) void k_edge_fadj_fb(
    const float* __restrict__ vals, const int* __restrict__ rows,
    const int* __restrict__ cols,
    const float* __restrict__ muh, const float* __restrict__ varh,
    const int* __restrict__ ffield,
    float* __restrict__ out0, float* __restrict__ out1, int nnz) {
  int wave = (int)((blockIdx.x * blockDim.x + threadIdx.x) >> 6);
  int lane = threadIdx.x & 63;
  int nw = (int)((gridDim.x * blockDim.x) >> 6);
  for (int e = wave; e < nnz; e += nw) {
    float w = vals[e];
    int r = rows[e];
    int f = ffield[cols[e]];
    float4 mb = ((const float4*)(muh  + (size_t)f * 256))[lane];
    float4 vb = ((const float4*)(varh + (size_t)f * 256))[lane];
    float w2 = w * w;
    float* om = out0 + (size_t)r * 512 + 256 + lane * 4;
    float* ov = out1 + (size_t)r * 512 + 256 + lane * 4;
    atomicAdd(om + 0, w * mb.x); atomicAdd(om + 1, w * mb.y);
    atomicAdd(om + 2, w * mb.z); atomicAdd(om + 3, w * mb.w);
    atomicAdd(ov + 0, w2 * vb.x); atomicAdd(ov + 1, w2 * vb.y);
    atomicAdd(ov + 2, w2 * vb.z); atomicAdd(ov + 3, w2 * vb.w);
  }
}

__global__ __launch_bounds__(256) void k_edge_madj_fb(
    const float* __restrict__ vals, const int* __restrict__ rows,
    const int* __restrict__ cols,
    const float* __restrict__ var, const float* __restrict__ varh,
    const int* __restrict__ ifield,
    float* __restrict__ out1, int nnz) {
  int wave = (int)((blockIdx.x * blockDim.x + threadIdx.x) >> 6);
  int lane = threadIdx.x & 63;
  int nw = (int)((gridDim.x * blockDim.x) >> 6);
  for (int e = wave; e < nnz; e += nw) {
    float w = 2.0f * vals[e];
    int r = rows[e];
    int c = cols[e];
    int f = ifield[c];
    float4 v  = ((const float4*)(var  + (size_t)c * 256))[lane];
    float4 vh = ((const float4*)(varh + (size_t)f * 256))[lane];
    float4 x;
    float sb;
    sb = sqrtf(vh.x); x.x = (sqrtf(v.x) - sb) * sb;
    sb = sqrtf(vh.y); x.y = (sqrtf(v.y) - sb) * sb;
    sb = sqrtf(vh.z); x.z = (sqrtf(v.z) - sb) * sb;
    sb = sqrtf(vh.w); x.w = (sqrtf(v.w) - sb) * sb;
    float* ov = out1 + (size_t)r * 512 + 256 + lane * 4;
    atomicAdd(ov + 0, w * x.x); atomicAdd(ov + 1, w * x.y);
    atomicAdd(ov + 2, w * x.z); atomicAdd(ov + 3, w * x.w);
  }
}

__global__ __launch_bounds__(256) void k_final(float* __restrict__ out1, int n_out) {
  int total = n_out * 64;
  for (int i = blockIdx.x * blockDim.x + threadIdx.x; i < total;
       i += gridDim.x * blockDim.x) {
    int r = i >> 6;
    int q = i & 63;
    float4* p = (float4*)(out1 + (size_t)r * 512 + 256) + q;
    float4 v = *p;
    v.x = fmaxf(v.x, 0.f) + EPS_F;
    v.y = fmaxf(v.y, 0.f) + EPS_F;
    v.z = fmaxf(v.z, 0.f) + EPS_F;
    v.w = fmaxf(v.w, 0.f) + EPS_F;
    *p = v;
  }
}

// ===========================================================================
extern "C" void kernel_launch(void* const* d_in, const int* in_sizes, int n_in_args,
                              void* d_out, int out_size, void* d_ws, size_t ws_size,
                              hipStream_t stream) {
  const float* mu        = (const float*)d_in[0];
  const float* var       = (const float*)d_in[1];
  const float* muh       = (const float*)d_in[2];
  const float* varh      = (const float*)d_in[3];
  const float* adj_vals  = (const float*)d_in[4];
  const float* fadj_vals = (const float*)d_in[5];
  const float* madj_vals = (const float*)d_in[6];
  const int* adj_rows    = (const int*)d_in[7];
  const int* adj_cols    = (const int*)d_in[8];
  const int* fadj_rows   = (const int*)d_in[9];
  const int* fadj_cols   = (const int*)d_in[10];
  const int* madj_rows   = (const int*)d_in[11];
  const int* madj_cols   = (const int*)d_in[12];
  const int* ifield      = (const int*)d_in[13];
  const int* ffield      = (const int*)d_in[14];

  const int n_out  = out_size / 1024;    // two outputs, 512 cols each
  const int n_in   = in_sizes[0] / 256;
  const int nnz    = in_sizes[4];
  const int n_full = in_sizes[14];       // ffield length

  float* out0 = (float*)d_out;
  float* out1 = out0 + (size_t)n_out * 512;

  // Workspace layout (u32 units): A, M, [FB], ord(uint2), cnt, base, cur
  const size_t uA = (size_t)n_in * 256;
  const size_t uM = (size_t)n_in * 128;
  const size_t uFB = (size_t)n_full * 256;
  const size_t uOrd = (size_t)3 * nnz * 2;
  const size_t uCnt = (size_t)3 * n_out;
  const size_t uBase = (size_t)3 * (n_out + 1);
  const size_t need2 = (uA + uM + uOrd + uCnt + uBase + uCnt) * sizeof(u32);
  const size_t need1 = need2 + uFB * sizeof(u32);

  if (ws_size >= need2) {
    const bool fb = (ws_size >= need1);
    u32* A = (u32*)d_ws;
    u32* M = A + uA;
    u32* FB = M + uM;                       // only valid if fb
    u32* tail = fb ? (FB + uFB) : (M + uM);
    uint2* ord = (uint2*)tail;
    int* cnt  = (int*)(tail + uOrd);
    int* base = cnt + uCnt;
    int* cur  = base + uBase;

    (void)hipMemsetAsync(cnt, 0, uCnt * sizeof(int), stream);
    k_count<<<1024, 256, 0, stream>>>(adj_rows, fadj_rows, madj_rows, cnt, nnz, n_out);
    k_scan3<<<3, 256, 0, stream>>>(cnt, base, cur, n_out);
    if (fb) {
      k_pre_scatter<true><<<2048, 256, 0, stream>>>(
          mu, var, muh, varh, ifield, ffield,
          adj_rows, adj_cols, adj_vals, fadj_rows, fadj_cols, fadj_vals,
          madj_rows, madj_cols, madj_vals,
          cur, ord, A, M, FB, n_in, n_full, n_out, nnz);
    } else {
      k_pre_scatter<false><<<2048, 256, 0, stream>>>(
          mu, var, muh, varh, ifield, ffield,
          adj_rows, adj_cols, adj_vals, fadj_rows, fadj_cols, fadj_vals,
          madj_rows, madj_cols, madj_vals,
          cur, ord, A, M, nullptr, n_in, n_full, n_out, nnz);
    }
    int blocks = (n_out * 64 + 255) / 256;
    if (fb) {
      k_agg<true><<<blocks, 256, 0, stream>>>(mu, var, muh, varh, A, M, FB, base, ord,
                                              out0, out1, n_out, nnz);
    } else {
      k_agg<false><<<blocks, 256, 0, stream>>>(mu, var, muh, varh, A, M, nullptr, base, ord,
                                               out0, out1, n_out, nnz);
    }
  } else {
    k_init_out<<<n_out, 256, 0, stream>>>(mu, var, out0, out1);
    k_edge_adj_fb<<<4096, 256, 0, stream>>>(adj_vals, adj_rows, adj_cols,
                                            mu, var, muh, varh, ifield, out0, out1, nnz);
    k_edge_madj_fb<<<4096, 256, 0, stream>>>(madj_vals, madj_rows, madj_cols,
                                             var, varh, ifield, out1, nnz);
    k_edge_fadj_fb<<<4096, 256, 0, stream>>>(fadj_vals, fadj_rows, fadj_cols,
                                             muh, varh, ffield, out0, out1, nnz);
    k_final<<<4096, 256, 0, stream>>>(out1, n_out);
  }
}